// Round 3
// baseline (1306.391 us; speedup 1.0000x reference)
//
#include <hip/hip_runtime.h>

constexpr int NN = 100000;   // nodes
constexpr int NE = 1250000;  // edges
constexpr int KDIM = 128;    // IN_DIM
constexpr int HID = 64;

constexpr int NPB = 128;                      // nodes per bucket
constexpr int NB  = (NN + NPB - 1) / NPB;     // 782 buckets
constexpr int NBP = 1024;                     // padded bin count (pow2 scan)
constexpr int BIN_BLOCKS = 64;
constexpr int BIN_CHUNK  = (NE + BIN_BLOCKS - 1) / BIN_BLOCKS;  // 19532
constexpr int EPT = (BIN_CHUNK + 1023) / 1024;                  // 20 edges/thread

// ---------------- zero the bucket histogram ----------------
__global__ void k_zero(int* __restrict__ total) {
    int i = blockIdx.x * blockDim.x + threadIdx.x;
    if (i < NBP) total[i] = 0;
}

// ---------------- bucket histogram of dst ----------------
__global__ __launch_bounds__(256) void k_hist(const int* __restrict__ dst,
                                              int* __restrict__ total) {
    __shared__ int h[NBP];
    for (int i = threadIdx.x; i < NBP; i += 256) h[i] = 0;
    __syncthreads();
    for (int e = blockIdx.x * 256 + threadIdx.x; e < NE; e += gridDim.x * 256)
        atomicAdd(&h[dst[e] >> 7], 1);
    __syncthreads();
    for (int i = threadIdx.x; i < NBP; i += 256)
        if (h[i]) atomicAdd(&total[i], h[i]);
}

// ---------------- exclusive scan of 1024 bins -> base, gcur ----------------
__global__ __launch_bounds__(1024) void k_scan(const int* __restrict__ total,
                                               int* __restrict__ base,
                                               int* __restrict__ gcur) {
    __shared__ int sh[NBP];
    const int t = threadIdx.x;
    int v = total[t];
    sh[t] = v;
    __syncthreads();
    int val = v;
    for (int off = 1; off < NBP; off <<= 1) {
        int add = (t >= off) ? sh[t - off] : 0;
        __syncthreads();
        val += add;
        sh[t] = val;
        __syncthreads();
    }
    base[t] = val - v;   // exclusive; base[NB] == NE (bins >= NB are empty)
    gcur[t] = val - v;
}

// ---------------- bin edges into bucket-grouped pack ----------------
// pack word = src | (dst & 127) << 17   (src < 2^17, dloc < 2^7)
__global__ __launch_bounds__(1024) void k_bin(const int* __restrict__ src,
                                              const int* __restrict__ dst,
                                              int* __restrict__ gcur,
                                              unsigned* __restrict__ pack) {
    __shared__ int cnt[NBP], rnk[NBP], gbase[NBP];
    const int t = threadIdx.x;
    for (int i = t; i < NBP; i += 1024) { cnt[i] = 0; rnk[i] = 0; }
    __syncthreads();
    const int c0 = blockIdx.x * BIN_CHUNK;
    int b[EPT];
    unsigned val[EPT];
#pragma unroll
    for (int i = 0; i < EPT; ++i) {
        int idx = i * 1024 + t;
        int e = c0 + idx;
        b[i] = -1;
        if (idx < BIN_CHUNK && e < NE) {
            int d = dst[e], s = src[e];
            int bb = d >> 7;
            b[i] = bb;
            val[i] = (unsigned)s | ((unsigned)(d & 127) << 17);
            atomicAdd(&cnt[bb], 1);
        }
    }
    __syncthreads();
    for (int i = t; i < NBP; i += 1024) {
        int c = cnt[i];
        if (c) gbase[i] = atomicAdd(&gcur[i], c);  // one reservation per (block,bucket)
    }
    __syncthreads();
#pragma unroll
    for (int i = 0; i < EPT; ++i) {
        if (b[i] >= 0) {
            int r = atomicAdd(&rnk[b[i]], 1);      // LDS rank within run
            pack[gbase[b[i]] + r] = val[i];        // ~25-word contiguous runs
        }
    }
}

// ---------------- per-node degree -> dinv (from bucket-grouped pack) ----------------
__global__ __launch_bounds__(256) void k_deg(const unsigned* __restrict__ pack,
                                             const int* __restrict__ base,
                                             float* __restrict__ dinv) {
    __shared__ int h[NPB];
    const int t = threadIdx.x;
    const int bkt = blockIdx.x;
    if (t < NPB) h[t] = 0;
    __syncthreads();
    const int beg = base[bkt], end = base[bkt + 1];
    for (int i = beg + t; i < end; i += 256) atomicAdd(&h[(pack[i] >> 17) & 127], 1);
    __syncthreads();
    if (t < NPB) {
        int v = bkt * NPB + t;
        if (v < NN) dinv[v] = rsqrtf((float)(h[t] + 1));  // +1 self loop
    }
}

// ---------------- GEMM: g[N,64] = dinv[row] * (act(x)[N,K] @ W[K,64]) ----------------
template <int K, bool RELU_IN>
__global__ __launch_bounds__(128) void k_gemm(const float* __restrict__ x,
                                              const float* __restrict__ W,
                                              const float* __restrict__ dinv,
                                              float* __restrict__ out) {
    __shared__ float Bs[K * HID];
    __shared__ float As[16][128];
    const int t = threadIdx.x;
    for (int i = t; i < K * HID; i += 128) Bs[i] = W[i];

    const int row0 = blockIdx.x * 128;
    const int ty = t >> 3;
    const int tx = t & 7;
    float acc[8][8] = {};

    for (int k0 = 0; k0 < K; k0 += 16) {
        __syncthreads();
        for (int i = t; i < 512; i += 128) {
            int r = i >> 2, q = i & 3;
            int row = row0 + r;
            float4 xv = make_float4(0.f, 0.f, 0.f, 0.f);
            if (row < NN) xv = *(const float4*)(x + row * K + k0 + q * 4);
            if (RELU_IN) {
                xv.x = fmaxf(xv.x, 0.f); xv.y = fmaxf(xv.y, 0.f);
                xv.z = fmaxf(xv.z, 0.f); xv.w = fmaxf(xv.w, 0.f);
            }
            As[q * 4 + 0][r] = xv.x; As[q * 4 + 1][r] = xv.y;
            As[q * 4 + 2][r] = xv.z; As[q * 4 + 3][r] = xv.w;
        }
        __syncthreads();
#pragma unroll
        for (int kk = 0; kk < 16; ++kk) {
            float4 a0 = *(const float4*)&As[kk][ty * 8];
            float4 a1 = *(const float4*)&As[kk][ty * 8 + 4];
            float4 b0 = *(const float4*)&Bs[(k0 + kk) * HID + tx * 8];
            float4 b1 = *(const float4*)&Bs[(k0 + kk) * HID + tx * 8 + 4];
            float a[8] = {a0.x, a0.y, a0.z, a0.w, a1.x, a1.y, a1.z, a1.w};
            float b[8] = {b0.x, b0.y, b0.z, b0.w, b1.x, b1.y, b1.z, b1.w};
#pragma unroll
            for (int m = 0; m < 8; ++m)
#pragma unroll
                for (int n = 0; n < 8; ++n) acc[m][n] += a[m] * b[n];
        }
    }

#pragma unroll
    for (int m = 0; m < 8; ++m) {
        int row = row0 + ty * 8 + m;
        if (row < NN) {
            float dv = dinv[row];
            float4 o0 = make_float4(dv * acc[m][0], dv * acc[m][1], dv * acc[m][2], dv * acc[m][3]);
            float4 o1 = make_float4(dv * acc[m][4], dv * acc[m][5], dv * acc[m][6], dv * acc[m][7]);
            *(float4*)(out + row * HID + tx * 8)     = o0;
            *(float4*)(out + row * HID + tx * 8 + 4) = o1;
        }
    }
}

// ---------------- bucket aggregation with LDS-privatized output ----------------
// out[v][j] = dinv[v] * ( sum_{s in N(v)} g[s][j] + g[v][j] ) + b[j]
__global__ __launch_bounds__(512) void k_agg(const unsigned* __restrict__ pack,
                                             const int* __restrict__ base,
                                             const float* __restrict__ dinv,
                                             const float* __restrict__ g,
                                             const float* __restrict__ bias,
                                             float* __restrict__ out) {
    __shared__ float tile[NPB * HID];  // 32 KB
    const int t = threadIdx.x;
    const int bkt = blockIdx.x;
    const int j = t & 63;
    const int w = t >> 6;  // wave 0..7
    for (int i = t; i < NPB * HID; i += 512) tile[i] = 0.f;
    const float bj = bias[j];
    __syncthreads();
    const int beg = base[bkt], end = base[bkt + 1];
    for (int k = beg + w; k < end; k += 8) {
        unsigned p = pack[k];                     // wave-uniform broadcast
        int s = p & 0x1FFFF;
        int dloc = (p >> 17) & 127;
        atomicAdd(&tile[dloc * HID + j], g[s * HID + j]);  // ds_add_f32, 2-way bank = free
    }
    __syncthreads();
    const int n0 = bkt * NPB;
#pragma unroll
    for (int m = 0; m < NPB / 8; ++m) {
        int vloc = w + m * 8;
        int v = n0 + vloc;
        if (v < NN)
            out[v * HID + j] = dinv[v] * (tile[vloc * HID + j] + g[v * HID + j]) + bj;
    }
}

// ---------------- launch ----------------
extern "C" void kernel_launch(void* const* d_in, const int* in_sizes, int n_in,
                              void* d_out, int out_size, void* d_ws, size_t ws_size,
                              hipStream_t stream) {
    const float* x  = (const float*)d_in[0];
    const int*   ei = (const int*)d_in[1];
    const float* W1 = (const float*)d_in[2];
    const float* b1 = (const float*)d_in[3];
    const float* W2 = (const float*)d_in[4];
    const float* b2 = (const float*)d_in[5];
    float* out = (float*)d_out;
    (void)in_sizes; (void)n_in; (void)out_size; (void)ws_size;

    const int* src = ei;
    const int* dst = ei + NE;

    // Workspace (~32 MB, < 38 MB proven in R2):
    char* ws = (char*)d_ws;
    int*      total = (int*)(ws + 0x000000);    // 4 KB
    int*      base  = (int*)(ws + 0x001000);    // 4 KB
    int*      gcur  = (int*)(ws + 0x002000);    // 4 KB
    float*    dinv  = (float*)(ws + 0x010000);  // 400 KB
    unsigned* pack  = (unsigned*)(ws + 0x100000); // 5 MB
    float*    g     = (float*)(ws + 0x600000);  // 25.6 MB
    float*    out1  = out;   // layer-1 output lives in d_out (dead after gemm2 reads it)

    // bucket build
    k_zero<<<(NBP + 255) / 256, 256, 0, stream>>>(total);
    k_hist<<<64, 256, 0, stream>>>(dst, total);
    k_scan<<<1, NBP, 0, stream>>>(total, base, gcur);
    k_bin<<<BIN_BLOCKS, 1024, 0, stream>>>(src, dst, gcur, pack);
    k_deg<<<NB, 256, 0, stream>>>(pack, base, dinv);

    // layer 1: g = dinv * (x @ W1); out1 = dinv*(sum g + g_self) + b1
    k_gemm<KDIM, false><<<(NN + 127) / 128, 128, 0, stream>>>(x, W1, dinv, g);
    k_agg<<<NB, 512, 0, stream>>>(pack, base, dinv, g, b1, out1);

    // layer 2: g = dinv * (relu(out1) @ W2); out = dinv*(sum g + g_self) + b2
    k_gemm<HID, true><<<(NN + 127) / 128, 128, 0, stream>>>(out1, W2, dinv, g);
    k_agg<<<NB, 512, 0, stream>>>(pack, base, dinv, g, b2, out);
}

// Round 4
// 329.547 us; speedup vs baseline: 3.9642x; 3.9642x over previous
//
#include <hip/hip_runtime.h>

constexpr int NN = 100000;   // nodes
constexpr int NE = 1250000;  // edges
constexpr int KDIM = 128;    // IN_DIM
constexpr int HID = 64;

constexpr int NPB = 128;                      // nodes per bucket
constexpr int NB  = (NN + NPB - 1) / NPB;     // 782 buckets
constexpr int NBP = 1024;                     // padded bin count (pow2 scan)
constexpr int BIN_BLOCKS = 64;
constexpr int BIN_CHUNK  = (NE + BIN_BLOCKS - 1) / BIN_BLOCKS;  // 19532
constexpr int EPT = (BIN_CHUNK + 1023) / 1024;                  // 20 edges/thread

// ---------------- zero the bucket histogram ----------------
__global__ void k_zero(int* __restrict__ total) {
    int i = blockIdx.x * blockDim.x + threadIdx.x;
    if (i < NBP) total[i] = 0;
}

// ---------------- bucket histogram of dst ----------------
__global__ __launch_bounds__(256) void k_hist(const int* __restrict__ dst,
                                              int* __restrict__ total) {
    __shared__ int h[NBP];
    for (int i = threadIdx.x; i < NBP; i += 256) h[i] = 0;
    __syncthreads();
    for (int e = blockIdx.x * 256 + threadIdx.x; e < NE; e += gridDim.x * 256)
        atomicAdd(&h[dst[e] >> 7], 1);
    __syncthreads();
    for (int i = threadIdx.x; i < NBP; i += 256)
        if (h[i]) atomicAdd(&total[i], h[i]);
}

// ---------------- exclusive scan of 1024 bins -> base, gcur ----------------
__global__ __launch_bounds__(1024) void k_scan(const int* __restrict__ total,
                                               int* __restrict__ base,
                                               int* __restrict__ gcur) {
    __shared__ int sh[NBP];
    const int t = threadIdx.x;
    int v = total[t];
    sh[t] = v;
    __syncthreads();
    int val = v;
    for (int off = 1; off < NBP; off <<= 1) {
        int add = (t >= off) ? sh[t - off] : 0;
        __syncthreads();
        val += add;
        sh[t] = val;
        __syncthreads();
    }
    base[t] = val - v;   // exclusive; base[NB] == NE (bins >= NB are empty)
    gcur[t] = val - v;
}

// ---------------- bin edges into bucket-grouped pack1 ----------------
// pack1 word = src | (dst & 127) << 17   (src < 2^17, dloc < 2^7)
__global__ __launch_bounds__(1024) void k_bin(const int* __restrict__ src,
                                              const int* __restrict__ dst,
                                              int* __restrict__ gcur,
                                              unsigned* __restrict__ pack1) {
    __shared__ int cnt[NBP], rnk[NBP], gbase[NBP];
    const int t = threadIdx.x;
    for (int i = t; i < NBP; i += 1024) { cnt[i] = 0; rnk[i] = 0; }
    __syncthreads();
    const int c0 = blockIdx.x * BIN_CHUNK;
    int b[EPT];
    unsigned val[EPT];
#pragma unroll
    for (int i = 0; i < EPT; ++i) {
        int idx = i * 1024 + t;
        int e = c0 + idx;
        b[i] = -1;
        if (idx < BIN_CHUNK && e < NE) {
            int d = dst[e], s = src[e];
            int bb = d >> 7;
            b[i] = bb;
            val[i] = (unsigned)s | ((unsigned)(d & 127) << 17);
            atomicAdd(&cnt[bb], 1);
        }
    }
    __syncthreads();
    for (int i = t; i < NBP; i += 1024) {
        int c = cnt[i];
        if (c) gbase[i] = atomicAdd(&gcur[i], c);  // one reservation per (block,bucket)
    }
    __syncthreads();
#pragma unroll
    for (int i = 0; i < EPT; ++i) {
        if (b[i] >= 0) {
            int r = atomicAdd(&rnk[b[i]], 1);      // LDS rank within run
            pack1[gbase[b[i]] + r] = val[i];       // ~25-word contiguous runs
        }
    }
}

// ---------------- per-bucket sort: pack1 -> node-sorted pack2 + row_start + dinv ----
__global__ __launch_bounds__(256) void k_sort(const unsigned* __restrict__ pack1,
                                              const int* __restrict__ base,
                                              unsigned* __restrict__ pack2,
                                              int* __restrict__ row_start,
                                              float* __restrict__ dinv) {
    __shared__ int h[NPB];    // counts, then write cursors
    __shared__ int sh[NPB];   // scan scratch
    const int t = threadIdx.x;
    const int bkt = blockIdx.x;
    if (t < NPB) h[t] = 0;
    __syncthreads();
    const int beg = base[bkt], end = base[bkt + 1];
    for (int i = beg + t; i < end; i += 256)
        atomicAdd(&h[(pack1[i] >> 17) & 127], 1);
    __syncthreads();
    int v0 = 0;
    if (t < NPB) { v0 = h[t]; sh[t] = v0; }
    __syncthreads();
    int val = v0;
    for (int off = 1; off < NPB; off <<= 1) {
        int add = (t < NPB && t >= off) ? sh[t - off] : 0;
        __syncthreads();
        if (t < NPB) { val += add; sh[t] = val; }
        __syncthreads();
    }
    if (t < NPB) {
        int start = beg + (val - v0);   // exclusive prefix within bucket
        int node = bkt * NPB + t;
        if (node < NN) {
            row_start[node] = start;
            dinv[node] = rsqrtf((float)(v0 + 1));  // +1 self loop
        }
        h[t] = start;  // reuse as write cursor
    }
    if (bkt == NB - 1 && t == 0) row_start[NN] = NE;
    __syncthreads();
    for (int i = beg + t; i < end; i += 256) {
        unsigned p = pack1[i];
        int pos = atomicAdd(&h[(p >> 17) & 127], 1);
        pack2[pos] = p & 0x1FFFF;      // writes stay inside this bucket's ~6KB region
    }
}

// ---------------- GEMM: g[N,64] = dinv[row] * (act(x)[N,K] @ W[K,64]) ----------------
template <int K, bool RELU_IN>
__global__ __launch_bounds__(128) void k_gemm(const float* __restrict__ x,
                                              const float* __restrict__ W,
                                              const float* __restrict__ dinv,
                                              float* __restrict__ out) {
    __shared__ float Bs[K * HID];
    __shared__ float As[16][128];
    const int t = threadIdx.x;
    for (int i = t; i < K * HID; i += 128) Bs[i] = W[i];

    const int row0 = blockIdx.x * 128;
    const int ty = t >> 3;
    const int tx = t & 7;
    float acc[8][8] = {};

    for (int k0 = 0; k0 < K; k0 += 16) {
        __syncthreads();
        for (int i = t; i < 512; i += 128) {
            int r = i >> 2, q = i & 3;
            int row = row0 + r;
            float4 xv = make_float4(0.f, 0.f, 0.f, 0.f);
            if (row < NN) xv = *(const float4*)(x + row * K + k0 + q * 4);
            if (RELU_IN) {
                xv.x = fmaxf(xv.x, 0.f); xv.y = fmaxf(xv.y, 0.f);
                xv.z = fmaxf(xv.z, 0.f); xv.w = fmaxf(xv.w, 0.f);
            }
            As[q * 4 + 0][r] = xv.x; As[q * 4 + 1][r] = xv.y;
            As[q * 4 + 2][r] = xv.z; As[q * 4 + 3][r] = xv.w;
        }
        __syncthreads();
#pragma unroll
        for (int kk = 0; kk < 16; ++kk) {
            float4 a0 = *(const float4*)&As[kk][ty * 8];
            float4 a1 = *(const float4*)&As[kk][ty * 8 + 4];
            float4 b0 = *(const float4*)&Bs[(k0 + kk) * HID + tx * 8];
            float4 b1 = *(const float4*)&Bs[(k0 + kk) * HID + tx * 8 + 4];
            float a[8] = {a0.x, a0.y, a0.z, a0.w, a1.x, a1.y, a1.z, a1.w};
            float b[8] = {b0.x, b0.y, b0.z, b0.w, b1.x, b1.y, b1.z, b1.w};
#pragma unroll
            for (int m = 0; m < 8; ++m)
#pragma unroll
                for (int n = 0; n < 8; ++n) acc[m][n] += a[m] * b[n];
        }
    }

#pragma unroll
    for (int m = 0; m < 8; ++m) {
        int row = row0 + ty * 8 + m;
        if (row < NN) {
            float dv = dinv[row];
            float4 o0 = make_float4(dv * acc[m][0], dv * acc[m][1], dv * acc[m][2], dv * acc[m][3]);
            float4 o1 = make_float4(dv * acc[m][4], dv * acc[m][5], dv * acc[m][6], dv * acc[m][7]);
            *(float4*)(out + row * HID + tx * 8)     = o0;
            *(float4*)(out + row * HID + tx * 8 + 4) = o1;
        }
    }
}

// ---------------- aggregation: one wave per node, register accumulate ----------------
// out[v][j] = dinv[v] * ( sum_{s in N(v)} g[s][j] + g[v][j] ) + b[j]
__global__ __launch_bounds__(256) void k_agg(const unsigned* __restrict__ pack2,
                                             const int* __restrict__ row_start,
                                             const float* __restrict__ dinv,
                                             const float* __restrict__ g,
                                             const float* __restrict__ bias,
                                             float* __restrict__ out) {
    const int v = blockIdx.x * 4 + (threadIdx.x >> 6);
    const int j = threadIdx.x & 63;
    if (v >= NN) return;
    const int beg = row_start[v];
    const int cnt = row_start[v + 1] - beg;
    const float dv = dinv[v];
    const float self = g[v * HID + j];
    int pre = 0;
    if (j < cnt) pre = (int)pack2[beg + j];   // coalesced cooperative preload
    const int n0 = cnt < 64 ? cnt : 64;
    float sum = 0.f;
    int k = 0;
    for (; k + 4 <= n0; k += 4) {             // 4 independent gathers in flight
        int s0 = __shfl(pre, k);
        int s1 = __shfl(pre, k + 1);
        int s2 = __shfl(pre, k + 2);
        int s3 = __shfl(pre, k + 3);
        float a0 = g[s0 * HID + j];
        float a1 = g[s1 * HID + j];
        float a2 = g[s2 * HID + j];
        float a3 = g[s3 * HID + j];
        sum += a0; sum += a1; sum += a2; sum += a3;
    }
    for (; k < n0; ++k) sum += g[__shfl(pre, k) * HID + j];
    for (int kk = 64; kk < cnt; ++kk)         // deg > 64: essentially never here
        sum += g[(int)pack2[beg + kk] * HID + j];
    out[v * HID + j] = dv * (sum + self) + bias[j];
}

// ---------------- launch ----------------
extern "C" void kernel_launch(void* const* d_in, const int* in_sizes, int n_in,
                              void* d_out, int out_size, void* d_ws, size_t ws_size,
                              hipStream_t stream) {
    const float* x  = (const float*)d_in[0];
    const int*   ei = (const int*)d_in[1];
    const float* W1 = (const float*)d_in[2];
    const float* b1 = (const float*)d_in[3];
    const float* W2 = (const float*)d_in[4];
    const float* b2 = (const float*)d_in[5];
    float* out = (float*)d_out;
    (void)in_sizes; (void)n_in; (void)out_size; (void)ws_size;

    const int* src = ei;
    const int* dst = ei + NE;

    // Workspace (~37 MB; 38.2 MB proven available in R2):
    char* ws = (char*)d_ws;
    int*      total     = (int*)(ws + 0x000000);    // 4 KB
    int*      base      = (int*)(ws + 0x001000);    // 4 KB
    int*      gcur      = (int*)(ws + 0x002000);    // 4 KB
    float*    dinv      = (float*)(ws + 0x010000);  // 400 KB
    int*      row_start = (int*)(ws + 0x080000);    // 400 KB + 4 (NN+1 entries)
    unsigned* pack1     = (unsigned*)(ws + 0x100000); // 5 MB
    unsigned* pack2     = (unsigned*)(ws + 0x600000); // 5 MB
    float*    g         = (float*)(ws + 0xB00000);  // 25.6 MB
    float*    out1 = out;  // layer-1 result lives in d_out (dead after gemm2 reads it)

    // CSR build: histogram -> scan -> bucket-bin -> in-bucket sort
    k_zero<<<(NBP + 255) / 256, 256, 0, stream>>>(total);
    k_hist<<<64, 256, 0, stream>>>(dst, total);
    k_scan<<<1, NBP, 0, stream>>>(total, base, gcur);
    k_bin<<<BIN_BLOCKS, 1024, 0, stream>>>(src, dst, gcur, pack1);
    k_sort<<<NB, 256, 0, stream>>>(pack1, base, pack2, row_start, dinv);

    // layer 1: g = dinv*(x @ W1); out1 = dinv*(sum_N g + g_self) + b1
    k_gemm<KDIM, false><<<(NN + 127) / 128, 128, 0, stream>>>(x, W1, dinv, g);
    k_agg<<<(NN + 3) / 4, 256, 0, stream>>>(pack2, row_start, dinv, g, b1, out1);

    // layer 2: g = dinv*(relu(out1) @ W2); out = dinv*(sum_N g + g_self) + b2
    k_gemm<HID, true><<<(NN + 127) / 128, 128, 0, stream>>>(out1, W2, dinv, g);
    k_agg<<<(NN + 3) / 4, 256, 0, stream>>>(pack2, row_start, dinv, g, b2, out);
}

// Round 5
// 296.713 us; speedup vs baseline: 4.4029x; 1.1107x over previous
//
#include <hip/hip_runtime.h>

constexpr int NN = 100000;   // nodes
constexpr int NE = 1250000;  // edges
constexpr int KDIM = 128;    // IN_DIM
constexpr int HID = 64;

constexpr int NPB = 128;                      // nodes per bucket
constexpr int NB  = (NN + NPB - 1) / NPB;     // 782 buckets
constexpr int NBP = 1024;                     // padded bin count (pow2 scan)
constexpr int BIN_BLOCKS = 64;
constexpr int BIN_CHUNK  = (NE + BIN_BLOCKS - 1) / BIN_BLOCKS;  // 19532
constexpr int EPT = (BIN_CHUNK + 1023) / 1024;                  // 20 edges/thread

// ---------------- zero the bucket histogram ----------------
__global__ void k_zero(int* __restrict__ total) {
    int i = blockIdx.x * blockDim.x + threadIdx.x;
    if (i < NBP) total[i] = 0;
}

// ---------------- bucket histogram of dst ----------------
__global__ __launch_bounds__(256) void k_hist(const int* __restrict__ dst,
                                              int* __restrict__ total) {
    __shared__ int h[NBP];
    for (int i = threadIdx.x; i < NBP; i += 256) h[i] = 0;
    __syncthreads();
    for (int e = blockIdx.x * 256 + threadIdx.x; e < NE; e += gridDim.x * 256)
        atomicAdd(&h[dst[e] >> 7], 1);
    __syncthreads();
    for (int i = threadIdx.x; i < NBP; i += 256)
        if (h[i]) atomicAdd(&total[i], h[i]);
}

// ---------------- exclusive scan of 1024 bins -> base, gcur ----------------
__global__ __launch_bounds__(1024) void k_scan(const int* __restrict__ total,
                                               int* __restrict__ base,
                                               int* __restrict__ gcur) {
    __shared__ int sh[NBP];
    const int t = threadIdx.x;
    int v = total[t];
    sh[t] = v;
    __syncthreads();
    int val = v;
    for (int off = 1; off < NBP; off <<= 1) {
        int add = (t >= off) ? sh[t - off] : 0;
        __syncthreads();
        val += add;
        sh[t] = val;
        __syncthreads();
    }
    base[t] = val - v;   // exclusive; base[NB] == NE (bins >= NB are empty)
    gcur[t] = val - v;
}

// ---------------- bin edges into bucket-grouped pack1 ----------------
// pack1 word = src | (dst & 127) << 17   (src < 2^17, dloc < 2^7)
__global__ __launch_bounds__(1024) void k_bin(const int* __restrict__ src,
                                              const int* __restrict__ dst,
                                              int* __restrict__ gcur,
                                              unsigned* __restrict__ pack1) {
    __shared__ int cnt[NBP], rnk[NBP], gbase[NBP];
    const int t = threadIdx.x;
    for (int i = t; i < NBP; i += 1024) { cnt[i] = 0; rnk[i] = 0; }
    __syncthreads();
    const int c0 = blockIdx.x * BIN_CHUNK;
    int b[EPT];
    unsigned val[EPT];
#pragma unroll
    for (int i = 0; i < EPT; ++i) {
        int idx = i * 1024 + t;
        int e = c0 + idx;
        b[i] = -1;
        if (idx < BIN_CHUNK && e < NE) {
            int d = dst[e], s = src[e];
            int bb = d >> 7;
            b[i] = bb;
            val[i] = (unsigned)s | ((unsigned)(d & 127) << 17);
            atomicAdd(&cnt[bb], 1);
        }
    }
    __syncthreads();
    for (int i = t; i < NBP; i += 1024) {
        int c = cnt[i];
        if (c) gbase[i] = atomicAdd(&gcur[i], c);  // one reservation per (block,bucket)
    }
    __syncthreads();
#pragma unroll
    for (int i = 0; i < EPT; ++i) {
        if (b[i] >= 0) {
            int r = atomicAdd(&rnk[b[i]], 1);      // LDS rank within run
            pack1[gbase[b[i]] + r] = val[i];       // ~25-word contiguous runs
        }
    }
}

// ---------------- per-bucket sort: pack1 -> node-sorted pack2 + row_start + dinv ----
__global__ __launch_bounds__(256) void k_sort(const unsigned* __restrict__ pack1,
                                              const int* __restrict__ base,
                                              unsigned* __restrict__ pack2,
                                              int* __restrict__ row_start,
                                              float* __restrict__ dinv) {
    __shared__ int h[NPB];    // counts, then write cursors
    __shared__ int sh[NPB];   // scan scratch
    const int t = threadIdx.x;
    const int bkt = blockIdx.x;
    if (t < NPB) h[t] = 0;
    __syncthreads();
    const int beg = base[bkt], end = base[bkt + 1];
    for (int i = beg + t; i < end; i += 256)
        atomicAdd(&h[(pack1[i] >> 17) & 127], 1);
    __syncthreads();
    int v0 = 0;
    if (t < NPB) { v0 = h[t]; sh[t] = v0; }
    __syncthreads();
    int val = v0;
    for (int off = 1; off < NPB; off <<= 1) {
        int add = (t < NPB && t >= off) ? sh[t - off] : 0;
        __syncthreads();
        if (t < NPB) { val += add; sh[t] = val; }
        __syncthreads();
    }
    if (t < NPB) {
        int start = beg + (val - v0);   // exclusive prefix within bucket
        int node = bkt * NPB + t;
        if (node < NN) {
            row_start[node] = start;
            dinv[node] = rsqrtf((float)(v0 + 1));  // +1 self loop
        }
        h[t] = start;  // reuse as write cursor
    }
    if (bkt == NB - 1 && t == 0) row_start[NN] = NE;
    __syncthreads();
    for (int i = beg + t; i < end; i += 256) {
        unsigned p = pack1[i];
        int pos = atomicAdd(&h[(p >> 17) & 127], 1);
        pack2[pos] = p & 0x1FFFF;      // writes stay inside this bucket's ~6KB region
    }
}

// ---------------- GEMM: g[N,64] = dinv[row] * (act(x)[N,K] @ W[K,64]) ----------------
// BM=64 rows/block, BK=32, 256 threads, 4x4 micro-tile. 1563 blocks (vs 782 in R4)
// and only 16.9 KB LDS -> high occupancy. As stride 68 keeps ds_read_b128 16B-aligned
// while spreading k-rows across banks.
template <int K, bool RELU_IN>
__global__ __launch_bounds__(256) void k_gemm(const float* __restrict__ x,
                                              const float* __restrict__ W,
                                              const float* __restrict__ dinv,
                                              float* __restrict__ out) {
    __shared__ float As[32][68];   // [kk][row], padded stride 68
    __shared__ float Bs[32][64];   // [kk][col]
    const int t = threadIdx.x;
    const int row0 = blockIdx.x * 64;
    const int tx = t & 15;         // 16 col-groups * 4 cols
    const int ty = t >> 4;         // 16 row-groups * 4 rows
    float acc[4][4] = {};

    for (int k0 = 0; k0 < K; k0 += 32) {
        __syncthreads();
        // stage A: 64 rows x 32 k = 512 float4, transposed into As
#pragma unroll
        for (int i = t; i < 512; i += 256) {
            int r = i >> 3, q = i & 7;
            int row = row0 + r;
            float4 xv = make_float4(0.f, 0.f, 0.f, 0.f);
            if (row < NN) xv = *(const float4*)(x + row * K + k0 + q * 4);
            if (RELU_IN) {
                xv.x = fmaxf(xv.x, 0.f); xv.y = fmaxf(xv.y, 0.f);
                xv.z = fmaxf(xv.z, 0.f); xv.w = fmaxf(xv.w, 0.f);
            }
            As[q * 4 + 0][r] = xv.x; As[q * 4 + 1][r] = xv.y;
            As[q * 4 + 2][r] = xv.z; As[q * 4 + 3][r] = xv.w;
        }
        // stage B: 32 k x 64 cols = 512 float4, natural layout (conflict-free)
#pragma unroll
        for (int i = t; i < 512; i += 256) {
            int kk = i >> 4, c4 = (i & 15) * 4;
            *(float4*)&Bs[kk][c4] = *(const float4*)(W + (k0 + kk) * HID + c4);
        }
        __syncthreads();
#pragma unroll
        for (int kk = 0; kk < 32; ++kk) {
            float4 av = *(const float4*)&As[kk][ty * 4];
            float4 bv = *(const float4*)&Bs[kk][tx * 4];
            float a[4] = {av.x, av.y, av.z, av.w};
            float b[4] = {bv.x, bv.y, bv.z, bv.w};
#pragma unroll
            for (int m = 0; m < 4; ++m)
#pragma unroll
                for (int n = 0; n < 4; ++n) acc[m][n] += a[m] * b[n];
        }
    }

#pragma unroll
    for (int m = 0; m < 4; ++m) {
        int row = row0 + ty * 4 + m;
        if (row < NN) {
            float dv = dinv[row];
            float4 o = make_float4(dv * acc[m][0], dv * acc[m][1],
                                   dv * acc[m][2], dv * acc[m][3]);
            *(float4*)(out + row * HID + tx * 4) = o;
        }
    }
}

// ---------------- aggregation: one wave per node, register accumulate ----------------
// out[v][j] = dinv[v] * ( sum_{s in N(v)} g[s][j] + g[v][j] ) + b[j]
__global__ __launch_bounds__(256) void k_agg(const unsigned* __restrict__ pack2,
                                             const int* __restrict__ row_start,
                                             const float* __restrict__ dinv,
                                             const float* __restrict__ g,
                                             const float* __restrict__ bias,
                                             float* __restrict__ out) {
    const int v = blockIdx.x * 4 + (threadIdx.x >> 6);
    const int j = threadIdx.x & 63;
    if (v >= NN) return;
    const int beg = row_start[v];
    const int cnt = row_start[v + 1] - beg;
    const float dv = dinv[v];
    const float self = g[v * HID + j];
    int pre = 0;
    if (j < cnt) pre = (int)pack2[beg + j];   // coalesced cooperative preload
    const int n0 = cnt < 64 ? cnt : 64;
    float sum = 0.f;
    int k = 0;
    for (; k + 8 <= n0; k += 8) {             // 8 independent gathers in flight
        int s0 = __shfl(pre, k),     s1 = __shfl(pre, k + 1);
        int s2 = __shfl(pre, k + 2), s3 = __shfl(pre, k + 3);
        int s4 = __shfl(pre, k + 4), s5 = __shfl(pre, k + 5);
        int s6 = __shfl(pre, k + 6), s7 = __shfl(pre, k + 7);
        float a0 = g[s0 * HID + j], a1 = g[s1 * HID + j];
        float a2 = g[s2 * HID + j], a3 = g[s3 * HID + j];
        float a4 = g[s4 * HID + j], a5 = g[s5 * HID + j];
        float a6 = g[s6 * HID + j], a7 = g[s7 * HID + j];
        sum += a0; sum += a1; sum += a2; sum += a3;
        sum += a4; sum += a5; sum += a6; sum += a7;
    }
    for (; k + 4 <= n0; k += 4) {
        int s0 = __shfl(pre, k),     s1 = __shfl(pre, k + 1);
        int s2 = __shfl(pre, k + 2), s3 = __shfl(pre, k + 3);
        float a0 = g[s0 * HID + j], a1 = g[s1 * HID + j];
        float a2 = g[s2 * HID + j], a3 = g[s3 * HID + j];
        sum += a0; sum += a1; sum += a2; sum += a3;
    }
    for (; k < n0; ++k) sum += g[__shfl(pre, k) * HID + j];
    for (int kk = 64; kk < cnt; ++kk)         // deg > 64: essentially never here
        sum += g[(int)pack2[beg + kk] * HID + j];
    out[v * HID + j] = dv * (sum + self) + bias[j];
}

// ---------------- launch ----------------
extern "C" void kernel_launch(void* const* d_in, const int* in_sizes, int n_in,
                              void* d_out, int out_size, void* d_ws, size_t ws_size,
                              hipStream_t stream) {
    const float* x  = (const float*)d_in[0];
    const int*   ei = (const int*)d_in[1];
    const float* W1 = (const float*)d_in[2];
    const float* b1 = (const float*)d_in[3];
    const float* W2 = (const float*)d_in[4];
    const float* b2 = (const float*)d_in[5];
    float* out = (float*)d_out;
    (void)in_sizes; (void)n_in; (void)out_size; (void)ws_size;

    const int* src = ei;
    const int* dst = ei + NE;

    // Workspace (~37 MB; 38.2 MB proven available in R2):
    char* ws = (char*)d_ws;
    int*      total     = (int*)(ws + 0x000000);    // 4 KB
    int*      base      = (int*)(ws + 0x001000);    // 4 KB
    int*      gcur      = (int*)(ws + 0x002000);    // 4 KB
    float*    dinv      = (float*)(ws + 0x010000);  // 400 KB
    int*      row_start = (int*)(ws + 0x080000);    // 400 KB + 4 (NN+1 entries)
    unsigned* pack1     = (unsigned*)(ws + 0x100000); // 5 MB
    unsigned* pack2     = (unsigned*)(ws + 0x600000); // 5 MB
    float*    g         = (float*)(ws + 0xB00000);  // 25.6 MB
    float*    out1 = out;  // layer-1 result lives in d_out (dead after gemm2 reads it)

    // CSR build: histogram -> scan -> bucket-bin -> in-bucket sort
    k_zero<<<(NBP + 255) / 256, 256, 0, stream>>>(total);
    k_hist<<<64, 256, 0, stream>>>(dst, total);
    k_scan<<<1, NBP, 0, stream>>>(total, base, gcur);
    k_bin<<<BIN_BLOCKS, 1024, 0, stream>>>(src, dst, gcur, pack1);
    k_sort<<<NB, 256, 0, stream>>>(pack1, base, pack2, row_start, dinv);

    // layer 1: g = dinv*(x @ W1); out1 = dinv*(sum_N g + g_self) + b1
    k_gemm<KDIM, false><<<(NN + 63) / 64, 256, 0, stream>>>(x, W1, dinv, g);
    k_agg<<<(NN + 3) / 4, 256, 0, stream>>>(pack2, row_start, dinv, g, b1, out1);

    // layer 2: g = dinv*(relu(out1) @ W2); out = dinv*(sum_N g + g_self) + b2
    k_gemm<HID, true><<<(NN + 63) / 64, 256, 0, stream>>>(out1, W2, dinv, g);
    k_agg<<<(NN + 3) / 4, 256, 0, stream>>>(pack2, row_start, dinv, g, b2, out);
}

// Round 6
// 271.964 us; speedup vs baseline: 4.8035x; 1.0910x over previous
//
#include <hip/hip_runtime.h>
#include <hip/hip_fp16.h>

constexpr int NN = 100000;   // nodes
constexpr int NE = 1250000;  // edges
constexpr int KDIM = 128;    // IN_DIM
constexpr int HID = 64;

constexpr int NPB = 128;                      // nodes per bucket
constexpr int NB  = (NN + NPB - 1) / NPB;     // 782 buckets
constexpr int NBP = 1024;                     // padded bin count (pow2 scan)
constexpr int BIN_BLOCKS = 64;
constexpr int BIN_CHUNK  = (NE + BIN_BLOCKS - 1) / BIN_BLOCKS;  // 19532
constexpr int EPT = (BIN_CHUNK + 1023) / 1024;                  // 20 edges/thread

// ---------------- zero the bucket histogram ----------------
__global__ void k_zero(int* __restrict__ total) {
    int i = blockIdx.x * blockDim.x + threadIdx.x;
    if (i < NBP) total[i] = 0;
}

// ---------------- bucket histogram of dst ----------------
__global__ __launch_bounds__(256) void k_hist(const int* __restrict__ dst,
                                              int* __restrict__ total) {
    __shared__ int h[NBP];
    for (int i = threadIdx.x; i < NBP; i += 256) h[i] = 0;
    __syncthreads();
    for (int e = blockIdx.x * 256 + threadIdx.x; e < NE; e += gridDim.x * 256)
        atomicAdd(&h[dst[e] >> 7], 1);
    __syncthreads();
    for (int i = threadIdx.x; i < NBP; i += 256)
        if (h[i]) atomicAdd(&total[i], h[i]);
}

// ---------------- exclusive scan of 1024 bins -> base, gcur ----------------
__global__ __launch_bounds__(1024) void k_scan(const int* __restrict__ total,
                                               int* __restrict__ base,
                                               int* __restrict__ gcur) {
    __shared__ int sh[NBP];
    const int t = threadIdx.x;
    int v = total[t];
    sh[t] = v;
    __syncthreads();
    int val = v;
    for (int off = 1; off < NBP; off <<= 1) {
        int add = (t >= off) ? sh[t - off] : 0;
        __syncthreads();
        val += add;
        sh[t] = val;
        __syncthreads();
    }
    base[t] = val - v;   // exclusive; base[NB] == NE (bins >= NB are empty)
    gcur[t] = val - v;
}

// ---------------- bin edges into bucket-grouped pack1 ----------------
// pack1 word = src | (dst & 127) << 17   (src < 2^17, dloc < 2^7)
__global__ __launch_bounds__(1024) void k_bin(const int* __restrict__ src,
                                              const int* __restrict__ dst,
                                              int* __restrict__ gcur,
                                              unsigned* __restrict__ pack1) {
    __shared__ int cnt[NBP], rnk[NBP], gbase[NBP];
    const int t = threadIdx.x;
    for (int i = t; i < NBP; i += 1024) { cnt[i] = 0; rnk[i] = 0; }
    __syncthreads();
    const int c0 = blockIdx.x * BIN_CHUNK;
    int b[EPT];
    unsigned val[EPT];
#pragma unroll
    for (int i = 0; i < EPT; ++i) {
        int idx = i * 1024 + t;
        int e = c0 + idx;
        b[i] = -1;
        if (idx < BIN_CHUNK && e < NE) {
            int d = dst[e], s = src[e];
            int bb = d >> 7;
            b[i] = bb;
            val[i] = (unsigned)s | ((unsigned)(d & 127) << 17);
            atomicAdd(&cnt[bb], 1);
        }
    }
    __syncthreads();
    for (int i = t; i < NBP; i += 1024) {
        int c = cnt[i];
        if (c) gbase[i] = atomicAdd(&gcur[i], c);  // one reservation per (block,bucket)
    }
    __syncthreads();
#pragma unroll
    for (int i = 0; i < EPT; ++i) {
        if (b[i] >= 0) {
            int r = atomicAdd(&rnk[b[i]], 1);      // LDS rank within run
            pack1[gbase[b[i]] + r] = val[i];       // ~25-word contiguous runs
        }
    }
}

// ---------------- per-bucket sort: pack1 -> node-sorted pack2 + row_start + dinv ----
__global__ __launch_bounds__(256) void k_sort(const unsigned* __restrict__ pack1,
                                              const int* __restrict__ base,
                                              unsigned* __restrict__ pack2,
                                              int* __restrict__ row_start,
                                              float* __restrict__ dinv) {
    __shared__ int h[NPB];    // counts, then write cursors
    __shared__ int sh[NPB];   // scan scratch
    const int t = threadIdx.x;
    const int bkt = blockIdx.x;
    if (t < NPB) h[t] = 0;
    __syncthreads();
    const int beg = base[bkt], end = base[bkt + 1];
    for (int i = beg + t; i < end; i += 256)
        atomicAdd(&h[(pack1[i] >> 17) & 127], 1);
    __syncthreads();
    int v0 = 0;
    if (t < NPB) { v0 = h[t]; sh[t] = v0; }
    __syncthreads();
    int val = v0;
    for (int off = 1; off < NPB; off <<= 1) {
        int add = (t < NPB && t >= off) ? sh[t - off] : 0;
        __syncthreads();
        if (t < NPB) { val += add; sh[t] = val; }
        __syncthreads();
    }
    if (t < NPB) {
        int start = beg + (val - v0);   // exclusive prefix within bucket
        int node = bkt * NPB + t;
        if (node < NN) {
            row_start[node] = start;
            dinv[node] = rsqrtf((float)(v0 + 1));  // +1 self loop
        }
        h[t] = start;  // reuse as write cursor
    }
    if (bkt == NB - 1 && t == 0) row_start[NN] = NE;
    __syncthreads();
    for (int i = beg + t; i < end; i += 256) {
        unsigned p = pack1[i];
        int pos = atomicAdd(&h[(p >> 17) & 127], 1);
        pack2[pos] = p & 0x1FFFF;      // writes stay inside this bucket's ~6KB region
    }
}

// ---------------- GEMM: g[N,64] = fp16( dinv[row] * (act(x)[N,K] @ W[K,64]) ) -------
// BM=64 rows/block, BK=32, 256 threads, 4x4 micro-tile.
struct h4 { __half2 a, b; };

template <int K, bool RELU_IN>
__global__ __launch_bounds__(256) void k_gemm(const float* __restrict__ x,
                                              const float* __restrict__ W,
                                              const float* __restrict__ dinv,
                                              __half* __restrict__ gout) {
    __shared__ float As[32][68];   // [kk][row], padded stride 68
    __shared__ float Bs[32][64];   // [kk][col]
    const int t = threadIdx.x;
    const int row0 = blockIdx.x * 64;
    const int tx = t & 15;         // 16 col-groups * 4 cols
    const int ty = t >> 4;         // 16 row-groups * 4 rows
    float acc[4][4] = {};

    for (int k0 = 0; k0 < K; k0 += 32) {
        __syncthreads();
#pragma unroll
        for (int i = t; i < 512; i += 256) {
            int r = i >> 3, q = i & 7;
            int row = row0 + r;
            float4 xv = make_float4(0.f, 0.f, 0.f, 0.f);
            if (row < NN) xv = *(const float4*)(x + row * K + k0 + q * 4);
            if (RELU_IN) {
                xv.x = fmaxf(xv.x, 0.f); xv.y = fmaxf(xv.y, 0.f);
                xv.z = fmaxf(xv.z, 0.f); xv.w = fmaxf(xv.w, 0.f);
            }
            As[q * 4 + 0][r] = xv.x; As[q * 4 + 1][r] = xv.y;
            As[q * 4 + 2][r] = xv.z; As[q * 4 + 3][r] = xv.w;
        }
#pragma unroll
        for (int i = t; i < 512; i += 256) {
            int kk = i >> 4, c4 = (i & 15) * 4;
            *(float4*)&Bs[kk][c4] = *(const float4*)(W + (k0 + kk) * HID + c4);
        }
        __syncthreads();
#pragma unroll
        for (int kk = 0; kk < 32; ++kk) {
            float4 av = *(const float4*)&As[kk][ty * 4];
            float4 bv = *(const float4*)&Bs[kk][tx * 4];
            float a[4] = {av.x, av.y, av.z, av.w};
            float b[4] = {bv.x, bv.y, bv.z, bv.w};
#pragma unroll
            for (int m = 0; m < 4; ++m)
#pragma unroll
                for (int n = 0; n < 4; ++n) acc[m][n] += a[m] * b[n];
        }
    }

#pragma unroll
    for (int m = 0; m < 4; ++m) {
        int row = row0 + ty * 4 + m;
        if (row < NN) {
            float dv = dinv[row];
            h4 o;
            o.a = __floats2half2_rn(dv * acc[m][0], dv * acc[m][1]);
            o.b = __floats2half2_rn(dv * acc[m][2], dv * acc[m][3]);
            *(h4*)(gout + row * HID + tx * 4) = o;   // 8B aligned store
        }
    }
}

// ---------------- aggregation: one wave per node, register accumulate ----------------
// out[v][j] = dinv[v] * ( sum_{s in N(v)} g[s][j] + g[v][j] ) + b[j]
__global__ __launch_bounds__(256) void k_agg(const unsigned* __restrict__ pack2,
                                             const int* __restrict__ row_start,
                                             const float* __restrict__ dinv,
                                             const __half* __restrict__ g,
                                             const float* __restrict__ bias,
                                             float* __restrict__ out) {
    const int v = blockIdx.x * 4 + (threadIdx.x >> 6);
    const int j = threadIdx.x & 63;
    if (v >= NN) return;
    const int beg = row_start[v];
    const int cnt = row_start[v + 1] - beg;
    const float dv = dinv[v];
    const float self = __half2float(g[v * HID + j]);
    int pre = 0;
    if (j < cnt) pre = (int)pack2[beg + j];   // coalesced cooperative preload
    const int n0 = cnt < 64 ? cnt : 64;
    float sum = 0.f;
    int k = 0;
    for (; k + 8 <= n0; k += 8) {             // 8 independent 128B wave gathers in flight
        int s0 = __shfl(pre, k),     s1 = __shfl(pre, k + 1);
        int s2 = __shfl(pre, k + 2), s3 = __shfl(pre, k + 3);
        int s4 = __shfl(pre, k + 4), s5 = __shfl(pre, k + 5);
        int s6 = __shfl(pre, k + 6), s7 = __shfl(pre, k + 7);
        __half a0 = g[s0 * HID + j], a1 = g[s1 * HID + j];
        __half a2 = g[s2 * HID + j], a3 = g[s3 * HID + j];
        __half a4 = g[s4 * HID + j], a5 = g[s5 * HID + j];
        __half a6 = g[s6 * HID + j], a7 = g[s7 * HID + j];
        sum += __half2float(a0); sum += __half2float(a1);
        sum += __half2float(a2); sum += __half2float(a3);
        sum += __half2float(a4); sum += __half2float(a5);
        sum += __half2float(a6); sum += __half2float(a7);
    }
    for (; k + 4 <= n0; k += 4) {
        int s0 = __shfl(pre, k),     s1 = __shfl(pre, k + 1);
        int s2 = __shfl(pre, k + 2), s3 = __shfl(pre, k + 3);
        __half a0 = g[s0 * HID + j], a1 = g[s1 * HID + j];
        __half a2 = g[s2 * HID + j], a3 = g[s3 * HID + j];
        sum += __half2float(a0); sum += __half2float(a1);
        sum += __half2float(a2); sum += __half2float(a3);
    }
    for (; k < n0; ++k) sum += __half2float(g[__shfl(pre, k) * HID + j]);
    for (int kk = 64; kk < cnt; ++kk)         // deg > 64: essentially never here
        sum += __half2float(g[(int)pack2[beg + kk] * HID + j]);
    out[v * HID + j] = dv * (sum + self) + bias[j];
}

// ---------------- launch ----------------
extern "C" void kernel_launch(void* const* d_in, const int* in_sizes, int n_in,
                              void* d_out, int out_size, void* d_ws, size_t ws_size,
                              hipStream_t stream) {
    const float* x  = (const float*)d_in[0];
    const int*   ei = (const int*)d_in[1];
    const float* W1 = (const float*)d_in[2];
    const float* b1 = (const float*)d_in[3];
    const float* W2 = (const float*)d_in[4];
    const float* b2 = (const float*)d_in[5];
    float* out = (float*)d_out;
    (void)in_sizes; (void)n_in; (void)out_size; (void)ws_size;

    const int* src = ei;
    const int* dst = ei + NE;

    // Workspace (~24 MB):
    char* ws = (char*)d_ws;
    int*      total     = (int*)(ws + 0x000000);    // 4 KB
    int*      base      = (int*)(ws + 0x001000);    // 4 KB
    int*      gcur      = (int*)(ws + 0x002000);    // 4 KB
    float*    dinv      = (float*)(ws + 0x010000);  // 400 KB
    int*      row_start = (int*)(ws + 0x080000);    // 400 KB + 4 (NN+1 entries)
    unsigned* pack1     = (unsigned*)(ws + 0x100000); // 5 MB
    unsigned* pack2     = (unsigned*)(ws + 0x600000); // 5 MB
    __half*   g         = (__half*)(ws + 0xB00000);  // 12.8 MB (fp16)
    float*    out1 = out;  // layer-1 result lives in d_out (dead after gemm2 reads it)

    // CSR build: histogram -> scan -> bucket-bin -> in-bucket sort
    k_zero<<<(NBP + 255) / 256, 256, 0, stream>>>(total);
    k_hist<<<64, 256, 0, stream>>>(dst, total);
    k_scan<<<1, NBP, 0, stream>>>(total, base, gcur);
    k_bin<<<BIN_BLOCKS, 1024, 0, stream>>>(src, dst, gcur, pack1);
    k_sort<<<NB, 256, 0, stream>>>(pack1, base, pack2, row_start, dinv);

    // layer 1: g = fp16(dinv*(x @ W1)); out1 = dinv*(sum_N g + g_self) + b1
    k_gemm<KDIM, false><<<(NN + 63) / 64, 256, 0, stream>>>(x, W1, dinv, g);
    k_agg<<<(NN + 3) / 4, 256, 0, stream>>>(pack2, row_start, dinv, g, b1, out1);

    // layer 2: g = fp16(dinv*(relu(out1) @ W2)); out = dinv*(sum_N g + g_self) + b2
    k_gemm<HID, true><<<(NN + 63) / 64, 256, 0, stream>>>(out1, W2, dinv, g);
    k_agg<<<(NN + 3) / 4, 256, 0, stream>>>(pack2, row_start, dinv, g, b2, out);
}

// Round 8
// 261.584 us; speedup vs baseline: 4.9941x; 1.0397x over previous
//
#include <hip/hip_runtime.h>
#include <hip/hip_fp16.h>

constexpr int NN = 100000;   // nodes
constexpr int NE = 1250000;  // edges
constexpr int KDIM = 128;    // IN_DIM
constexpr int HID = 64;

constexpr int NPB = 128;                      // nodes per bucket
constexpr int NB  = (NN + NPB - 1) / NPB;     // 782 buckets
constexpr int NBP = 1024;                     // padded bin count (pow2 scan)
constexpr int BIN_BLOCKS = 128;
constexpr int BIN_CHUNK  = (NE + BIN_BLOCKS - 1) / BIN_BLOCKS;  // 9766
constexpr int EPT = (BIN_CHUNK + 1023) / 1024;                  // 10 edges/thread

// ---------------- zero the bucket histogram ----------------
__global__ void k_zero(int* __restrict__ total) {
    int i = blockIdx.x * blockDim.x + threadIdx.x;
    if (i < NBP) total[i] = 0;
}

// ---------------- bucket histogram of dst ----------------
__global__ __launch_bounds__(256) void k_hist(const int* __restrict__ dst,
                                              int* __restrict__ total) {
    __shared__ int h[NBP];
    for (int i = threadIdx.x; i < NBP; i += 256) h[i] = 0;
    __syncthreads();
    for (int e = blockIdx.x * 256 + threadIdx.x; e < NE; e += gridDim.x * 256)
        atomicAdd(&h[dst[e] >> 7], 1);
    __syncthreads();
    for (int i = threadIdx.x; i < NBP; i += 256)
        if (h[i]) atomicAdd(&total[i], h[i]);
}

// ---------------- exclusive scan of 1024 bins -> base, gcur ----------------
__global__ __launch_bounds__(1024) void k_scan(const int* __restrict__ total,
                                               int* __restrict__ base,
                                               int* __restrict__ gcur) {
    __shared__ int sh[NBP];
    const int t = threadIdx.x;
    int v = total[t];
    sh[t] = v;
    __syncthreads();
    int val = v;
    for (int off = 1; off < NBP; off <<= 1) {
        int add = (t >= off) ? sh[t - off] : 0;
        __syncthreads();
        val += add;
        sh[t] = val;
        __syncthreads();
    }
    base[t] = val - v;   // exclusive; base[NB] == NE (bins >= NB are empty)
    gcur[t] = val - v;
}

// ---------------- bin edges into bucket-grouped pack1 ----------------
// pack1 word = src | (dst & 127) << 17   (src < 2^17, dloc < 2^7)
__global__ __launch_bounds__(1024) void k_bin(const int* __restrict__ src,
                                              const int* __restrict__ dst,
                                              int* __restrict__ gcur,
                                              unsigned* __restrict__ pack1) {
    __shared__ int cnt[NBP], rnk[NBP], gbase[NBP];
    const int t = threadIdx.x;
    for (int i = t; i < NBP; i += 1024) { cnt[i] = 0; rnk[i] = 0; }
    __syncthreads();
    const int c0 = blockIdx.x * BIN_CHUNK;
    int b[EPT];
    unsigned val[EPT];
#pragma unroll
    for (int i = 0; i < EPT; ++i) {
        int idx = i * 1024 + t;
        int e = c0 + idx;
        b[i] = -1;
        if (idx < BIN_CHUNK && e < NE) {
            int d = dst[e], s = src[e];
            int bb = d >> 7;
            b[i] = bb;
            val[i] = (unsigned)s | ((unsigned)(d & 127) << 17);
            atomicAdd(&cnt[bb], 1);
        }
    }
    __syncthreads();
    for (int i = t; i < NBP; i += 1024) {
        int c = cnt[i];
        if (c) gbase[i] = atomicAdd(&gcur[i], c);  // one reservation per (block,bucket)
    }
    __syncthreads();
#pragma unroll
    for (int i = 0; i < EPT; ++i) {
        if (b[i] >= 0) {
            int r = atomicAdd(&rnk[b[i]], 1);      // LDS rank within run
            pack1[gbase[b[i]] + r] = val[i];       // ~12-word contiguous runs
        }
    }
}

// ---------------- per-bucket sort: pack1 -> node-sorted pack2 + row_start + dinv ----
__global__ __launch_bounds__(256) void k_sort(const unsigned* __restrict__ pack1,
                                              const int* __restrict__ base,
                                              unsigned* __restrict__ pack2,
                                              int* __restrict__ row_start,
                                              float* __restrict__ dinv) {
    __shared__ int h[NPB];    // counts, then write cursors
    __shared__ int sh[NPB];   // scan scratch
    const int t = threadIdx.x;
    const int bkt = blockIdx.x;
    if (t < NPB) h[t] = 0;
    __syncthreads();
    const int beg = base[bkt], end = base[bkt + 1];
    for (int i = beg + t; i < end; i += 256)
        atomicAdd(&h[(pack1[i] >> 17) & 127], 1);
    __syncthreads();
    int v0 = 0;
    if (t < NPB) { v0 = h[t]; sh[t] = v0; }
    __syncthreads();
    int val = v0;
    for (int off = 1; off < NPB; off <<= 1) {
        int add = (t < NPB && t >= off) ? sh[t - off] : 0;
        __syncthreads();
        if (t < NPB) { val += add; sh[t] = val; }
        __syncthreads();
    }
    if (t < NPB) {
        int start = beg + (val - v0);   // exclusive prefix within bucket
        int node = bkt * NPB + t;
        if (node < NN) {
            row_start[node] = start;
            dinv[node] = rsqrtf((float)(v0 + 1));  // +1 self loop
        }
        h[t] = start;  // reuse as write cursor
    }
    if (bkt == NB - 1 && t == 0) row_start[NN] = NE;
    __syncthreads();
    for (int i = beg + t; i < end; i += 256) {
        unsigned p = pack1[i];
        int pos = atomicAdd(&h[(p >> 17) & 127], 1);
        pack2[pos] = p & 0x1FFFF;      // writes stay inside this bucket's ~6KB region
    }
}

// ---------------- GEMM: g[N,64] = fp16( dinv[row] * (act(x)[N,K] @ W[K,64]) ) -------
// BM=64 rows/block, BK=32, 256 threads, 4x4 micro-tile.
struct h4 { __half2 a, b; };

template <int K, bool RELU_IN>
__global__ __launch_bounds__(256) void k_gemm(const float* __restrict__ x,
                                              const float* __restrict__ W,
                                              const float* __restrict__ dinv,
                                              __half* __restrict__ gout) {
    __shared__ float As[32][68];   // [kk][row], padded stride 68
    __shared__ float Bs[32][64];   // [kk][col]
    const int t = threadIdx.x;
    const int row0 = blockIdx.x * 64;
    const int tx = t & 15;         // 16 col-groups * 4 cols
    const int ty = t >> 4;         // 16 row-groups * 4 rows
    float acc[4][4] = {};

    for (int k0 = 0; k0 < K; k0 += 32) {
        __syncthreads();
#pragma unroll
        for (int i = t; i < 512; i += 256) {
            int r = i >> 3, q = i & 7;
            int row = row0 + r;
            float4 xv = make_float4(0.f, 0.f, 0.f, 0.f);
            if (row < NN) xv = *(const float4*)(x + row * K + k0 + q * 4);
            if (RELU_IN) {
                xv.x = fmaxf(xv.x, 0.f); xv.y = fmaxf(xv.y, 0.f);
                xv.z = fmaxf(xv.z, 0.f); xv.w = fmaxf(xv.w, 0.f);
            }
            As[q * 4 + 0][r] = xv.x; As[q * 4 + 1][r] = xv.y;
            As[q * 4 + 2][r] = xv.z; As[q * 4 + 3][r] = xv.w;
        }
#pragma unroll
        for (int i = t; i < 512; i += 256) {
            int kk = i >> 4, c4 = (i & 15) * 4;
            *(float4*)&Bs[kk][c4] = *(const float4*)(W + (k0 + kk) * HID + c4);
        }
        __syncthreads();
#pragma unroll
        for (int kk = 0; kk < 32; ++kk) {
            float4 av = *(const float4*)&As[kk][ty * 4];
            float4 bv = *(const float4*)&Bs[kk][tx * 4];
            float a[4] = {av.x, av.y, av.z, av.w};
            float b[4] = {bv.x, bv.y, bv.z, bv.w};
#pragma unroll
            for (int m = 0; m < 4; ++m)
#pragma unroll
                for (int n = 0; n < 4; ++n) acc[m][n] += a[m] * b[n];
        }
    }

#pragma unroll
    for (int m = 0; m < 4; ++m) {
        int row = row0 + ty * 4 + m;
        if (row < NN) {
            float dv = dinv[row];
            h4 o;
            o.a = __floats2half2_rn(dv * acc[m][0], dv * acc[m][1]);
            o.b = __floats2half2_rn(dv * acc[m][2], dv * acc[m][3]);
            *(h4*)(gout + row * HID + tx * 4) = o;   // 8B aligned store
        }
    }
}

// ---------------- aggregation: wave per node, 4 edges per wave-load ----------------
// lane = 16*slot + sub: slot picks the edge, sub picks a 4-feature quad.
// Each lane gathers uint2 = 4 fp16 feats; one wave-load covers 4 edges.
// NOTE: every __shfl is executed in UNIFORM control flow (clamped index) —
// ds_bpermute from an exec-masked-off source lane returns undefined data
// (this was R7's correctness bug; deg=17 nodes read garbage for edge 16).
__global__ __launch_bounds__(256) void k_agg(const unsigned* __restrict__ pack2,
                                             const int* __restrict__ row_start,
                                             const float* __restrict__ dinv,
                                             const __half* __restrict__ g,
                                             const float* __restrict__ bias,
                                             float* __restrict__ out) {
    const int v = blockIdx.x * 4 + (threadIdx.x >> 6);
    if (v >= NN) return;
    const int lane = threadIdx.x & 63;
    const int sub  = lane & 15;   // feature quad: 4*sub .. 4*sub+3
    const int slot = lane >> 4;   // edge slot 0..3
    const int beg = row_start[v];
    const int cnt = row_start[v + 1] - beg;
    int pre = 0;
    if (lane < cnt) pre = (int)pack2[beg + lane];   // coalesced cooperative preload
    const int n0 = cnt < 64 ? cnt : 64;
    float4 acc = make_float4(0.f, 0.f, 0.f, 0.f);

    int k = 0;
    for (; k + 8 <= n0; k += 8) {       // uniform: all 64 lanes execute
        int sA = __shfl(pre, k + slot);
        int sB = __shfl(pre, k + 4 + slot);
        uint2 rA = *(const uint2*)(g + sA * HID + sub * 4);
        uint2 rB = *(const uint2*)(g + sB * HID + sub * 4);
        float2 a0 = __half22float2(*(const __half2*)&rA.x);
        float2 a1 = __half22float2(*(const __half2*)&rA.y);
        float2 b0 = __half22float2(*(const __half2*)&rB.x);
        float2 b1 = __half22float2(*(const __half2*)&rB.y);
        acc.x += a0.x + b0.x; acc.y += a0.y + b0.y;
        acc.z += a1.x + b1.x; acc.w += a1.y + b1.y;
    }
    for (; k < n0; k += 4) {            // tail: shfl hoisted OUT of divergence
        int idx  = k + slot;
        int idxc = idx < n0 ? idx : 0;  // clamp so source lane is always active
        int s = __shfl(pre, idxc);      // uniform execution
        if (idx < n0) {                 // divergence only around the gather+add
            uint2 r = *(const uint2*)(g + s * HID + sub * 4);
            float2 a0 = __half22float2(*(const __half2*)&r.x);
            float2 a1 = __half22float2(*(const __half2*)&r.y);
            acc.x += a0.x; acc.y += a0.y; acc.z += a1.x; acc.w += a1.y;
        }
    }
    for (int kk = 64 + slot; kk < cnt; kk += 4) {   // deg > 64: no shfl, safe
        int s = (int)pack2[beg + kk];
        uint2 r = *(const uint2*)(g + s * HID + sub * 4);
        float2 a0 = __half22float2(*(const __half2*)&r.x);
        float2 a1 = __half22float2(*(const __half2*)&r.y);
        acc.x += a0.x; acc.y += a0.y; acc.z += a1.x; acc.w += a1.y;
    }

    // reduce across the 4 slots (xor 16, 32) — uniform
#pragma unroll
    for (int m = 16; m <= 32; m <<= 1) {
        acc.x += __shfl_xor(acc.x, m);
        acc.y += __shfl_xor(acc.y, m);
        acc.z += __shfl_xor(acc.z, m);
        acc.w += __shfl_xor(acc.w, m);
    }

    if (slot == 0) {   // lanes 0..15 write float4 each: one 256B line
        const float dv = dinv[v];
        uint2 sr = *(const uint2*)(g + v * HID + sub * 4);
        float2 s0 = __half22float2(*(const __half2*)&sr.x);
        float2 s1 = __half22float2(*(const __half2*)&sr.y);
        float4 bv = *(const float4*)(bias + sub * 4);
        float4 o;
        o.x = dv * (acc.x + s0.x) + bv.x;
        o.y = dv * (acc.y + s0.y) + bv.y;
        o.z = dv * (acc.z + s1.x) + bv.z;
        o.w = dv * (acc.w + s1.y) + bv.w;
        *(float4*)(out + v * HID + sub * 4) = o;
    }
}

// ---------------- launch ----------------
extern "C" void kernel_launch(void* const* d_in, const int* in_sizes, int n_in,
                              void* d_out, int out_size, void* d_ws, size_t ws_size,
                              hipStream_t stream) {
    const float* x  = (const float*)d_in[0];
    const int*   ei = (const int*)d_in[1];
    const float* W1 = (const float*)d_in[2];
    const float* b1 = (const float*)d_in[3];
    const float* W2 = (const float*)d_in[4];
    const float* b2 = (const float*)d_in[5];
    float* out = (float*)d_out;
    (void)in_sizes; (void)n_in; (void)out_size; (void)ws_size;

    const int* src = ei;
    const int* dst = ei + NE;

    // Workspace (~24 MB):
    char* ws = (char*)d_ws;
    int*      total     = (int*)(ws + 0x000000);    // 4 KB
    int*      base      = (int*)(ws + 0x001000);    // 4 KB
    int*      gcur      = (int*)(ws + 0x002000);    // 4 KB
    float*    dinv      = (float*)(ws + 0x010000);  // 400 KB
    int*      row_start = (int*)(ws + 0x080000);    // 400 KB + 4 (NN+1 entries)
    unsigned* pack1     = (unsigned*)(ws + 0x100000); // 5 MB
    unsigned* pack2     = (unsigned*)(ws + 0x600000); // 5 MB
    __half*   g         = (__half*)(ws + 0xB00000);  // 12.8 MB (fp16)
    float*    out1 = out;  // layer-1 result lives in d_out (dead after gemm2 reads it)

    // CSR build: histogram -> scan -> bucket-bin -> in-bucket sort
    k_zero<<<(NBP + 255) / 256, 256, 0, stream>>>(total);
    k_hist<<<128, 256, 0, stream>>>(dst, total);
    k_scan<<<1, NBP, 0, stream>>>(total, base, gcur);
    k_bin<<<BIN_BLOCKS, 1024, 0, stream>>>(src, dst, gcur, pack1);
    k_sort<<<NB, 256, 0, stream>>>(pack1, base, pack2, row_start, dinv);

    // layer 1: g = fp16(dinv*(x @ W1)); out1 = dinv*(sum_N g + g_self) + b1
    k_gemm<KDIM, false><<<(NN + 63) / 64, 256, 0, stream>>>(x, W1, dinv, g);
    k_agg<<<(NN + 3) / 4, 256, 0, stream>>>(pack2, row_start, dinv, g, b1, out1);

    // layer 2: g = fp16(dinv*(relu(out1) @ W2)); out = dinv*(sum_N g + g_self) + b2
    k_gemm<HID, true><<<(NN + 63) / 64, 256, 0, stream>>>(out1, W2, dinv, g);
    k_agg<<<(NN + 3) / 4, 256, 0, stream>>>(pack2, row_start, dinv, g, b2, out);
}

// Round 9
// 240.622 us; speedup vs baseline: 5.4292x; 1.0871x over previous
//
#include <hip/hip_runtime.h>
#include <hip/hip_fp16.h>

constexpr int NN = 100000;   // nodes
constexpr int NE = 1250000;  // edges
constexpr int KDIM = 128;    // IN_DIM
constexpr int HID = 64;

constexpr int NPB = 128;                      // nodes per bucket
constexpr int NB  = (NN + NPB - 1) / NPB;     // 782 buckets
constexpr int NBP = 1024;                     // padded bin count (pow2 scan)
constexpr int BIN_BLOCKS = 256;
constexpr int BIN_CHUNK  = (NE + BIN_BLOCKS - 1) / BIN_BLOCKS;  // 4883
constexpr int EPT = (BIN_CHUNK + 1023) / 1024;                  // 5 edges/thread

using half8  = __attribute__((ext_vector_type(8))) _Float16;
using floatx4 = __attribute__((ext_vector_type(4))) float;

// ---------------- bucket histogram of dst ----------------
__global__ __launch_bounds__(256) void k_hist(const int* __restrict__ dst,
                                              int* __restrict__ total) {
    __shared__ int h[NBP];
    for (int i = threadIdx.x; i < NBP; i += 256) h[i] = 0;
    __syncthreads();
    for (int e = blockIdx.x * 256 + threadIdx.x; e < NE; e += gridDim.x * 256)
        atomicAdd(&h[dst[e] >> 7], 1);
    __syncthreads();
    for (int i = threadIdx.x; i < NBP; i += 256)
        if (h[i]) atomicAdd(&total[i], h[i]);
}

// ---------------- exclusive scan of 1024 bins -> base, gcur ----------------
__global__ __launch_bounds__(1024) void k_scan(const int* __restrict__ total,
                                               int* __restrict__ base,
                                               int* __restrict__ gcur) {
    __shared__ int sh[NBP];
    const int t = threadIdx.x;
    int v = total[t];
    sh[t] = v;
    __syncthreads();
    int val = v;
    for (int off = 1; off < NBP; off <<= 1) {
        int add = (t >= off) ? sh[t - off] : 0;
        __syncthreads();
        val += add;
        sh[t] = val;
        __syncthreads();
    }
    base[t] = val - v;   // exclusive; base[NB] == NE (bins >= NB are empty)
    gcur[t] = val - v;
}

// ---------------- bin edges into bucket-grouped pack1 ----------------
// pack1 word = src | (dst & 127) << 17   (src < 2^17, dloc < 2^7)
__global__ __launch_bounds__(1024) void k_bin(const int* __restrict__ src,
                                              const int* __restrict__ dst,
                                              int* __restrict__ gcur,
                                              unsigned* __restrict__ pack1) {
    __shared__ int cnt[NBP], rnk[NBP], gbase[NBP];
    const int t = threadIdx.x;
    for (int i = t; i < NBP; i += 1024) { cnt[i] = 0; rnk[i] = 0; }
    __syncthreads();
    const int c0 = blockIdx.x * BIN_CHUNK;
    int b[EPT];
    unsigned val[EPT];
#pragma unroll
    for (int i = 0; i < EPT; ++i) {
        int idx = i * 1024 + t;
        int e = c0 + idx;
        b[i] = -1;
        if (idx < BIN_CHUNK && e < NE) {
            int d = dst[e], s = src[e];
            int bb = d >> 7;
            b[i] = bb;
            val[i] = (unsigned)s | ((unsigned)(d & 127) << 17);
            atomicAdd(&cnt[bb], 1);
        }
    }
    __syncthreads();
    for (int i = t; i < NBP; i += 1024) {
        int c = cnt[i];
        if (c) gbase[i] = atomicAdd(&gcur[i], c);  // one reservation per (block,bucket)
    }
    __syncthreads();
#pragma unroll
    for (int i = 0; i < EPT; ++i) {
        if (b[i] >= 0) {
            int r = atomicAdd(&rnk[b[i]], 1);      // LDS rank within run
            pack1[gbase[b[i]] + r] = val[i];       // short contiguous runs
        }
    }
}

// ---------------- per-bucket sort: pack1 -> node-sorted pack2 + row_start + dinv ----
__global__ __launch_bounds__(256) void k_sort(const unsigned* __restrict__ pack1,
                                              const int* __restrict__ base,
                                              unsigned* __restrict__ pack2,
                                              int* __restrict__ row_start,
                                              float* __restrict__ dinv) {
    __shared__ int h[NPB];    // counts, then write cursors
    __shared__ int sh[NPB];   // scan scratch
    const int t = threadIdx.x;
    const int bkt = blockIdx.x;
    if (t < NPB) h[t] = 0;
    __syncthreads();
    const int beg = base[bkt], end = base[bkt + 1];
    for (int i = beg + t; i < end; i += 256)
        atomicAdd(&h[(pack1[i] >> 17) & 127], 1);
    __syncthreads();
    int v0 = 0;
    if (t < NPB) { v0 = h[t]; sh[t] = v0; }
    __syncthreads();
    int val = v0;
    for (int off = 1; off < NPB; off <<= 1) {
        int add = (t < NPB && t >= off) ? sh[t - off] : 0;
        __syncthreads();
        if (t < NPB) { val += add; sh[t] = val; }
        __syncthreads();
    }
    if (t < NPB) {
        int start = beg + (val - v0);   // exclusive prefix within bucket
        int node = bkt * NPB + t;
        if (node < NN) {
            row_start[node] = start;
            dinv[node] = rsqrtf((float)(v0 + 1));  // +1 self loop
        }
        h[t] = start;  // reuse as write cursor
    }
    if (bkt == NB - 1 && t == 0) row_start[NN] = NE;
    __syncthreads();
    for (int i = beg + t; i < end; i += 256) {
        unsigned p = pack1[i];
        int pos = atomicAdd(&h[(p >> 17) & 127], 1);
        pack2[pos] = p & 0x1FFFF;      // writes stay inside this bucket's region
    }
}

// ---------------- W prepack: frag-major fp16 for MFMA B-operand ----------------
// Whp[((ks*4+ct)*64 + lane)*8 + j] = f16( W[(ks*32 + (lane>>4)*8 + j)*64 + ct*16 + (lane&15)] )
template <int K>
__global__ __launch_bounds__(256) void k_wpack(const float* __restrict__ W,
                                               __half* __restrict__ Whp) {
    int t = blockIdx.x * 256 + threadIdx.x;
    if (t >= (K / 32) * 4 * 64) return;
    int lane = t & 63;
    int frag = t >> 6;            // ks*4 + ct
    int ks = frag >> 2, ct = frag & 3;
    int quad = lane >> 4, n = lane & 15;
    __half tmp[8];
#pragma unroll
    for (int j = 0; j < 8; ++j)
        tmp[j] = __float2half(W[(ks * 32 + quad * 8 + j) * HID + ct * 16 + n]);
    *(uint4*)(Whp + t * 8) = *(uint4*)tmp;
}

// ---------------- MFMA GEMM: g[N,64] = fp16( dinv[row] * (act(x)[N,K] @ W) ) -------
// Wave = 16 rows x 64 cols (4 col-tiles of 16x16x32 f16 MFMA). Block = 4 waves.
// A-frag: lane reads x[row0 + (lane&15)][ks*32 + quad*8 .. +7] (2 float4, cvt f16).
// B-frag: one coalesced 16B/lane load from frag-major Whp (L1-resident).
// D layout: col = lane&15 (+ct*16), row = quad*4 + reg.
template <int K, bool RELU_IN>
__global__ __launch_bounds__(256) void k_mm(const float* __restrict__ x,
                                            const __half* __restrict__ Whp,
                                            const float* __restrict__ dinv,
                                            __half* __restrict__ gout) {
    const int t = threadIdx.x;
    const int w = t >> 6, lane = t & 63;
    const int quad = lane >> 4, m = lane & 15;
    const int rowA = blockIdx.x * 64 + w * 16 + m;
    const bool rok = rowA < NN;
    const float* xr = x + (long)rowA * K + quad * 8;

    floatx4 acc[4] = {};
#pragma unroll
    for (int ks = 0; ks < K / 32; ++ks) {
        float xv[8];
        if (rok) {
            float4 p0 = *(const float4*)(xr + ks * 32);
            float4 p1 = *(const float4*)(xr + ks * 32 + 4);
            xv[0] = p0.x; xv[1] = p0.y; xv[2] = p0.z; xv[3] = p0.w;
            xv[4] = p1.x; xv[5] = p1.y; xv[6] = p1.z; xv[7] = p1.w;
        } else {
#pragma unroll
            for (int j = 0; j < 8; ++j) xv[j] = 0.f;
        }
        half8 a;
#pragma unroll
        for (int j = 0; j < 8; ++j) {
            float v = RELU_IN ? fmaxf(xv[j], 0.f) : xv[j];
            a[j] = (_Float16)v;
        }
#pragma unroll
        for (int ct = 0; ct < 4; ++ct) {
            half8 b = *(const half8*)(Whp + ((ks * 4 + ct) * 64 + lane) * 8);
            acc[ct] = __builtin_amdgcn_mfma_f32_16x16x32_f16(a, b, acc[ct], 0, 0, 0);
        }
    }

#pragma unroll
    for (int r = 0; r < 4; ++r) {
        int rowD = blockIdx.x * 64 + w * 16 + quad * 4 + r;
        if (rowD < NN) {
            float dv = dinv[rowD];
#pragma unroll
            for (int ct = 0; ct < 4; ++ct)
                gout[rowD * HID + ct * 16 + m] = __float2half(dv * acc[ct][r]);
        }
    }
}

// ---------------- aggregation: wave per node, 4 edges per wave-load ----------------
// lane = 16*slot + sub: slot picks the edge, sub picks a 4-feature quad.
// All __shfl in UNIFORM control flow (clamped index) — ds_bpermute from a
// masked-off source lane is undefined (R7's bug).
__global__ __launch_bounds__(256) void k_agg(const unsigned* __restrict__ pack2,
                                             const int* __restrict__ row_start,
                                             const float* __restrict__ dinv,
                                             const __half* __restrict__ g,
                                             const float* __restrict__ bias,
                                             float* __restrict__ out) {
    const int v = blockIdx.x * 4 + (threadIdx.x >> 6);
    if (v >= NN) return;
    const int lane = threadIdx.x & 63;
    const int sub  = lane & 15;   // feature quad: 4*sub .. 4*sub+3
    const int slot = lane >> 4;   // edge slot 0..3
    const int beg = row_start[v];
    const int cnt = row_start[v + 1] - beg;
    int pre = 0;
    if (lane < cnt) pre = (int)pack2[beg + lane];   // coalesced cooperative preload
    const int n0 = cnt < 64 ? cnt : 64;
    float4 acc = make_float4(0.f, 0.f, 0.f, 0.f);

    int k = 0;
    for (; k + 8 <= n0; k += 8) {       // uniform: all 64 lanes execute
        int sA = __shfl(pre, k + slot);
        int sB = __shfl(pre, k + 4 + slot);
        uint2 rA = *(const uint2*)(g + sA * HID + sub * 4);
        uint2 rB = *(const uint2*)(g + sB * HID + sub * 4);
        float2 a0 = __half22float2(*(const __half2*)&rA.x);
        float2 a1 = __half22float2(*(const __half2*)&rA.y);
        float2 b0 = __half22float2(*(const __half2*)&rB.x);
        float2 b1 = __half22float2(*(const __half2*)&rB.y);
        acc.x += a0.x + b0.x; acc.y += a0.y + b0.y;
        acc.z += a1.x + b1.x; acc.w += a1.y + b1.y;
    }
    for (; k < n0; k += 4) {            // tail: shfl hoisted OUT of divergence
        int idx  = k + slot;
        int idxc = idx < n0 ? idx : 0;
        int s = __shfl(pre, idxc);      // uniform execution
        if (idx < n0) {
            uint2 r = *(const uint2*)(g + s * HID + sub * 4);
            float2 a0 = __half22float2(*(const __half2*)&r.x);
            float2 a1 = __half22float2(*(const __half2*)&r.y);
            acc.x += a0.x; acc.y += a0.y; acc.z += a1.x; acc.w += a1.y;
        }
    }
    for (int kk = 64 + slot; kk < cnt; kk += 4) {   // deg > 64: no shfl, safe
        int s = (int)pack2[beg + kk];
        uint2 r = *(const uint2*)(g + s * HID + sub * 4);
        float2 a0 = __half22float2(*(const __half2*)&r.x);
        float2 a1 = __half22float2(*(const __half2*)&r.y);
        acc.x += a0.x; acc.y += a0.y; acc.z += a1.x; acc.w += a1.y;
    }

#pragma unroll
    for (int mm = 16; mm <= 32; mm <<= 1) {
        acc.x += __shfl_xor(acc.x, mm);
        acc.y += __shfl_xor(acc.y, mm);
        acc.z += __shfl_xor(acc.z, mm);
        acc.w += __shfl_xor(acc.w, mm);
    }

    if (slot == 0) {   // lanes 0..15 write float4 each: one 256B line
        const float dv = dinv[v];
        uint2 sr = *(const uint2*)(g + v * HID + sub * 4);
        float2 s0 = __half22float2(*(const __half2*)&sr.x);
        float2 s1 = __half22float2(*(const __half2*)&sr.y);
        float4 bv = *(const float4*)(bias + sub * 4);
        float4 o;
        o.x = dv * (acc.x + s0.x) + bv.x;
        o.y = dv * (acc.y + s0.y) + bv.y;
        o.z = dv * (acc.z + s1.x) + bv.z;
        o.w = dv * (acc.w + s1.y) + bv.w;
        *(float4*)(out + v * HID + sub * 4) = o;
    }
}

// ---------------- launch ----------------
extern "C" void kernel_launch(void* const* d_in, const int* in_sizes, int n_in,
                              void* d_out, int out_size, void* d_ws, size_t ws_size,
                              hipStream_t stream) {
    const float* x  = (const float*)d_in[0];
    const int*   ei = (const int*)d_in[1];
    const float* W1 = (const float*)d_in[2];
    const float* b1 = (const float*)d_in[3];
    const float* W2 = (const float*)d_in[4];
    const float* b2 = (const float*)d_in[5];
    float* out = (float*)d_out;
    (void)in_sizes; (void)n_in; (void)out_size; (void)ws_size;

    const int* src = ei;
    const int* dst = ei + NE;

    // Workspace (~24 MB):
    char* ws = (char*)d_ws;
    int*      total     = (int*)(ws + 0x000000);    // 4 KB
    int*      base      = (int*)(ws + 0x001000);    // 4 KB
    int*      gcur      = (int*)(ws + 0x002000);    // 4 KB
    __half*   Whp1      = (__half*)(ws + 0x004000); // 16 KB (frag-major W1)
    __half*   Whp2      = (__half*)(ws + 0x008000); // 8 KB  (frag-major W2)
    float*    dinv      = (float*)(ws + 0x010000);  // 400 KB
    int*      row_start = (int*)(ws + 0x080000);    // 400 KB + 4 (NN+1 entries)
    unsigned* pack1     = (unsigned*)(ws + 0x100000); // 5 MB
    unsigned* pack2     = (unsigned*)(ws + 0x600000); // 5 MB
    __half*   g         = (__half*)(ws + 0xB00000);  // 12.8 MB (fp16)
    float*    out1 = out;  // layer-1 result lives in d_out (dead after k_mm2 reads it)

    // CSR build: histogram -> scan -> bucket-bin -> in-bucket sort
    hipMemsetAsync(total, 0, NBP * sizeof(int), stream);
    k_hist<<<128, 256, 0, stream>>>(dst, total);
    k_scan<<<1, NBP, 0, stream>>>(total, base, gcur);
    k_bin<<<BIN_BLOCKS, 1024, 0, stream>>>(src, dst, gcur, pack1);
    k_sort<<<NB, 256, 0, stream>>>(pack1, base, pack2, row_start, dinv);

    // W prepack (tiny)
    k_wpack<KDIM><<<4, 256, 0, stream>>>(W1, Whp1);
    k_wpack<HID><<<2, 256, 0, stream>>>(W2, Whp2);

    // layer 1: g = fp16(dinv*(x @ W1)); out1 = dinv*(sum_N g + g_self) + b1
    k_mm<KDIM, false><<<(NN + 63) / 64, 256, 0, stream>>>(x, Whp1, dinv, g);
    k_agg<<<(NN + 3) / 4, 256, 0, stream>>>(pack2, row_start, dinv, g, b1, out1);

    // layer 2: g = fp16(dinv*(relu(out1) @ W2)); out = dinv*(sum_N g + g_self) + b2
    k_mm<HID, true><<<(NN + 63) / 64, 256, 0, stream>>>(out1, Whp2, dinv, g);
    k_agg<<<(NN + 3) / 4, 256, 0, stream>>>(pack2, row_start, dinv, g, b2, out);
}

// Round 10
// 228.257 us; speedup vs baseline: 5.7233x; 1.0542x over previous
//
#include <hip/hip_runtime.h>
#include <hip/hip_fp16.h>

constexpr int NN = 100000;   // nodes (== 6250 * 16, no remainder)
constexpr int NE = 1250000;  // edges
constexpr int KDIM = 128;    // IN_DIM
constexpr int HID = 64;

constexpr int NPB = 128;                      // nodes per bucket
constexpr int NB  = (NN + NPB - 1) / NPB;     // 782 buckets
constexpr int NBP = 1024;                     // padded bin count (pow2 scan)
constexpr int BIN_BLOCKS = 256;
constexpr int BIN_CHUNK  = (NE + BIN_BLOCKS - 1) / BIN_BLOCKS;  // 4883
constexpr int EPT = (BIN_CHUNK + 1023) / 1024;                  // 5 edges/thread

using half8   = __attribute__((ext_vector_type(8))) _Float16;
using floatx4 = __attribute__((ext_vector_type(4))) float;

// ---------------- prep: zero bins + frag-major fp16 W1/W2 packs ----------------
// Whp[((ks*4+ct)*64 + lane)*8 + j] = f16( W[(ks*32 + (lane>>4)*8 + j)*64 + ct*16 + (lane&15)] )
__global__ __launch_bounds__(256) void k_prep(const float* __restrict__ W1,
                                              const float* __restrict__ W2,
                                              __half* __restrict__ Whp1,
                                              __half* __restrict__ Whp2,
                                              int* __restrict__ total) {
    const int blk = blockIdx.x;
    if (blk < 4) {                      // W1: K=128 -> 16 frags * 64 lanes = 1024 items
        int t = blk * 256 + threadIdx.x;
        int lane = t & 63, frag = t >> 6;
        int ks = frag >> 2, ct = frag & 3;
        int quad = lane >> 4, n = lane & 15;
        __half tmp[8];
#pragma unroll
        for (int j = 0; j < 8; ++j)
            tmp[j] = __float2half(W1[(ks * 32 + quad * 8 + j) * HID + ct * 16 + n]);
        *(uint4*)(Whp1 + t * 8) = *(uint4*)tmp;
    } else if (blk < 6) {               // W2: K=64 -> 8 frags * 64 = 512 items
        int t = (blk - 4) * 256 + threadIdx.x;
        int lane = t & 63, frag = t >> 6;
        int ks = frag >> 2, ct = frag & 3;
        int quad = lane >> 4, n = lane & 15;
        __half tmp[8];
#pragma unroll
        for (int j = 0; j < 8; ++j)
            tmp[j] = __float2half(W2[(ks * 32 + quad * 8 + j) * HID + ct * 16 + n]);
        *(uint4*)(Whp2 + t * 8) = *(uint4*)tmp;
    } else {                            // zero the bucket histogram
        for (int i = threadIdx.x; i < NBP; i += 256) total[i] = 0;
    }
}

// ---------------- bucket histogram of dst ----------------
__global__ __launch_bounds__(256) void k_hist(const int* __restrict__ dst,
                                              int* __restrict__ total) {
    __shared__ int h[NBP];
    for (int i = threadIdx.x; i < NBP; i += 256) h[i] = 0;
    __syncthreads();
    for (int e = blockIdx.x * 256 + threadIdx.x; e < NE; e += gridDim.x * 256)
        atomicAdd(&h[dst[e] >> 7], 1);
    __syncthreads();
    for (int i = threadIdx.x; i < NBP; i += 256)
        if (h[i]) atomicAdd(&total[i], h[i]);
}

// ---------------- exclusive scan of 1024 bins -> base, gcur ----------------
__global__ __launch_bounds__(1024) void k_scan(const int* __restrict__ total,
                                               int* __restrict__ base,
                                               int* __restrict__ gcur) {
    __shared__ int sh[NBP];
    const int t = threadIdx.x;
    int v = total[t];
    sh[t] = v;
    __syncthreads();
    int val = v;
    for (int off = 1; off < NBP; off <<= 1) {
        int add = (t >= off) ? sh[t - off] : 0;
        __syncthreads();
        val += add;
        sh[t] = val;
        __syncthreads();
    }
    base[t] = val - v;   // exclusive; base[NB] == NE (bins >= NB are empty)
    gcur[t] = val - v;
}

// ---------------- bin edges into bucket-grouped pack1 ----------------
// pack1 word = src | (dst & 127) << 17   (src < 2^17, dloc < 2^7)
__global__ __launch_bounds__(1024) void k_bin(const int* __restrict__ src,
                                              const int* __restrict__ dst,
                                              int* __restrict__ gcur,
                                              unsigned* __restrict__ pack1) {
    __shared__ int cnt[NBP], rnk[NBP], gbase[NBP];
    const int t = threadIdx.x;
    for (int i = t; i < NBP; i += 1024) { cnt[i] = 0; rnk[i] = 0; }
    __syncthreads();
    const int c0 = blockIdx.x * BIN_CHUNK;
    int b[EPT];
    unsigned val[EPT];
#pragma unroll
    for (int i = 0; i < EPT; ++i) {
        int idx = i * 1024 + t;
        int e = c0 + idx;
        b[i] = -1;
        if (idx < BIN_CHUNK && e < NE) {
            int d = dst[e], s = src[e];
            int bb = d >> 7;
            b[i] = bb;
            val[i] = (unsigned)s | ((unsigned)(d & 127) << 17);
            atomicAdd(&cnt[bb], 1);
        }
    }
    __syncthreads();
    for (int i = t; i < NBP; i += 1024) {
        int c = cnt[i];
        if (c) gbase[i] = atomicAdd(&gcur[i], c);  // one reservation per (block,bucket)
    }
    __syncthreads();
#pragma unroll
    for (int i = 0; i < EPT; ++i) {
        if (b[i] >= 0) {
            int r = atomicAdd(&rnk[b[i]], 1);      // LDS rank within run
            pack1[gbase[b[i]] + r] = val[i];       // short contiguous runs
        }
    }
}

// ---------------- per-bucket sort: pack1 -> node-sorted pack2 + row_start + dinv ----
__global__ __launch_bounds__(256) void k_sort(const unsigned* __restrict__ pack1,
                                              const int* __restrict__ base,
                                              unsigned* __restrict__ pack2,
                                              int* __restrict__ row_start,
                                              float* __restrict__ dinv) {
    __shared__ int h[NPB];    // counts, then write cursors
    __shared__ int sh[NPB];   // scan scratch
    const int t = threadIdx.x;
    const int bkt = blockIdx.x;
    if (t < NPB) h[t] = 0;
    __syncthreads();
    const int beg = base[bkt], end = base[bkt + 1];
    for (int i = beg + t; i < end; i += 256)
        atomicAdd(&h[(pack1[i] >> 17) & 127], 1);
    __syncthreads();
    int v0 = 0;
    if (t < NPB) { v0 = h[t]; sh[t] = v0; }
    __syncthreads();
    int val = v0;
    for (int off = 1; off < NPB; off <<= 1) {
        int add = (t < NPB && t >= off) ? sh[t - off] : 0;
        __syncthreads();
        if (t < NPB) { val += add; sh[t] = val; }
        __syncthreads();
    }
    if (t < NPB) {
        int start = beg + (val - v0);   // exclusive prefix within bucket
        int node = bkt * NPB + t;
        if (node < NN) {
            row_start[node] = start;
            dinv[node] = rsqrtf((float)(v0 + 1));  // +1 self loop
        }
        h[t] = start;  // reuse as write cursor
    }
    if (bkt == NB - 1 && t == 0) row_start[NN] = NE;
    __syncthreads();
    for (int i = beg + t; i < end; i += 256) {
        unsigned p = pack1[i];
        int pos = atomicAdd(&h[(p >> 17) & 127], 1);
        pack2[pos] = p & 0x1FFFF;      // writes stay inside this bucket's region
    }
}

// ---------------- MFMA GEMM (layer 1): g1 = fp16( dinv * (x @ W1) ) ----------------
// Wave = 16 rows x 64 cols (4 col-tiles of 16x16x32 f16). Block = 4 waves.
template <int K>
__global__ __launch_bounds__(256) void k_mm(const float* __restrict__ x,
                                            const __half* __restrict__ Whp,
                                            const float* __restrict__ dinv,
                                            __half* __restrict__ gout) {
    const int t = threadIdx.x;
    const int w = t >> 6, lane = t & 63;
    const int quad = lane >> 4, m = lane & 15;
    const int rowA = blockIdx.x * 64 + w * 16 + m;
    const bool rok = rowA < NN;
    const float* xr = x + (long)rowA * K + quad * 8;

    floatx4 acc[4] = {};
#pragma unroll
    for (int ks = 0; ks < K / 32; ++ks) {
        float xv[8];
        if (rok) {
            float4 p0 = *(const float4*)(xr + ks * 32);
            float4 p1 = *(const float4*)(xr + ks * 32 + 4);
            xv[0] = p0.x; xv[1] = p0.y; xv[2] = p0.z; xv[3] = p0.w;
            xv[4] = p1.x; xv[5] = p1.y; xv[6] = p1.z; xv[7] = p1.w;
        } else {
#pragma unroll
            for (int j = 0; j < 8; ++j) xv[j] = 0.f;
        }
        half8 a;
#pragma unroll
        for (int j = 0; j < 8; ++j) a[j] = (_Float16)xv[j];
#pragma unroll
        for (int ct = 0; ct < 4; ++ct) {
            half8 b = *(const half8*)(Whp + ((ks * 4 + ct) * 64 + lane) * 8);
            acc[ct] = __builtin_amdgcn_mfma_f32_16x16x32_f16(a, b, acc[ct], 0, 0, 0);
        }
    }

#pragma unroll
    for (int r = 0; r < 4; ++r) {
        int rowD = blockIdx.x * 64 + w * 16 + quad * 4 + r;
        if (rowD < NN) {
            float dv = dinv[rowD];
#pragma unroll
            for (int ct = 0; ct < 4; ++ct)
                gout[rowD * HID + ct * 16 + m] = __float2half(dv * acc[ct][r]);
        }
    }
}

// ---------------- FUSED agg1 + mm2: g2 = fp16( dinv * (relu(agg1+b1) @ W2) ) -------
// Block = 256 threads = 4 waves; 16 nodes/block (4 per wave, sequential).
// Aggregation identical to k_agg (all shfl in uniform control flow — R7 lesson).
// relu(out1) -> fp16 LDS tile[16][72] (pad: 2-way banks, free) -> 2 MFMAs/wave.
__global__ __launch_bounds__(256) void k_aggmm(const unsigned* __restrict__ pack2,
                                               const int* __restrict__ row_start,
                                               const float* __restrict__ dinv,
                                               const __half* __restrict__ g1,
                                               const float* __restrict__ b1,
                                               const __half* __restrict__ Whp2,
                                               __half* __restrict__ g2) {
    __shared__ __half tile[16][72];
    const int w = threadIdx.x >> 6, lane = threadIdx.x & 63;
    const int sub = lane & 15, slot = lane >> 4;
    const int vbase = blockIdx.x * 16 + w * 4;
    const float4 bv = *(const float4*)(b1 + sub * 4);

#pragma unroll
    for (int i = 0; i < 4; ++i) {
        const int v = vbase + i;                   // NN % 16 == 0: always valid
        const int beg = row_start[v];
        const int cnt = row_start[v + 1] - beg;
        int pre = 0;
        if (lane < cnt) pre = (int)pack2[beg + lane];
        const int n0 = cnt < 64 ? cnt : 64;
        float4 acc = make_float4(0.f, 0.f, 0.f, 0.f);

        int k = 0;
        for (; k + 8 <= n0; k += 8) {              // uniform: all 64 lanes
            int sA = __shfl(pre, k + slot);
            int sB = __shfl(pre, k + 4 + slot);
            uint2 rA = *(const uint2*)(g1 + sA * HID + sub * 4);
            uint2 rB = *(const uint2*)(g1 + sB * HID + sub * 4);
            float2 a0 = __half22float2(*(const __half2*)&rA.x);
            float2 a1 = __half22float2(*(const __half2*)&rA.y);
            float2 b0 = __half22float2(*(const __half2*)&rB.x);
            float2 b1f = __half22float2(*(const __half2*)&rB.y);
            acc.x += a0.x + b0.x; acc.y += a0.y + b0.y;
            acc.z += a1.x + b1f.x; acc.w += a1.y + b1f.y;
        }
        for (; k < n0; k += 4) {                   // tail: shfl hoisted, clamped
            int idx  = k + slot;
            int idxc = idx < n0 ? idx : 0;
            int s = __shfl(pre, idxc);
            if (idx < n0) {
                uint2 r = *(const uint2*)(g1 + s * HID + sub * 4);
                float2 a0 = __half22float2(*(const __half2*)&r.x);
                float2 a1 = __half22float2(*(const __half2*)&r.y);
                acc.x += a0.x; acc.y += a0.y; acc.z += a1.x; acc.w += a1.y;
            }
        }
        for (int kk = 64 + slot; kk < cnt; kk += 4) {  // deg > 64: no shfl, safe
            int s = (int)pack2[beg + kk];
            uint2 r = *(const uint2*)(g1 + s * HID + sub * 4);
            float2 a0 = __half22float2(*(const __half2*)&r.x);
            float2 a1 = __half22float2(*(const __half2*)&r.y);
            acc.x += a0.x; acc.y += a0.y; acc.z += a1.x; acc.w += a1.y;
        }
#pragma unroll
        for (int mm = 16; mm <= 32; mm <<= 1) {
            acc.x += __shfl_xor(acc.x, mm);
            acc.y += __shfl_xor(acc.y, mm);
            acc.z += __shfl_xor(acc.z, mm);
            acc.w += __shfl_xor(acc.w, mm);
        }
        if (slot == 0) {                           // relu(out1) -> fp16 LDS row
            const float dv = dinv[v];
            uint2 sr = *(const uint2*)(g1 + v * HID + sub * 4);
            float2 s0 = __half22float2(*(const __half2*)&sr.x);
            float2 s1 = __half22float2(*(const __half2*)&sr.y);
            __half tmp[4];
            tmp[0] = __float2half(fmaxf(dv * (acc.x + s0.x) + bv.x, 0.f));
            tmp[1] = __float2half(fmaxf(dv * (acc.y + s0.y) + bv.y, 0.f));
            tmp[2] = __float2half(fmaxf(dv * (acc.z + s1.x) + bv.z, 0.f));
            tmp[3] = __float2half(fmaxf(dv * (acc.w + s1.y) + bv.w, 0.f));
            *(uint2*)&tile[w * 4 + i][sub * 4] = *(uint2*)tmp;
        }
    }
    __syncthreads();

    // mm2: wave w computes col-tile ct = w of rows [block*16, block*16+16)
    const int quad = slot, m = sub;
    floatx4 acc2 = {};
#pragma unroll
    for (int ks = 0; ks < 2; ++ks) {
        half8 a = *(const half8*)&tile[m][ks * 32 + quad * 8];
        half8 b = *(const half8*)(Whp2 + ((ks * 4 + w) * 64 + lane) * 8);
        acc2 = __builtin_amdgcn_mfma_f32_16x16x32_f16(a, b, acc2, 0, 0, 0);
    }
#pragma unroll
    for (int r = 0; r < 4; ++r) {
        int rowD = blockIdx.x * 16 + quad * 4 + r;
        g2[rowD * HID + w * 16 + m] = __float2half(dinv[rowD] * acc2[r]);
    }
}

// ---------------- final aggregation (layer 2): fp32 out ----------------
__global__ __launch_bounds__(256) void k_agg(const unsigned* __restrict__ pack2,
                                             const int* __restrict__ row_start,
                                             const float* __restrict__ dinv,
                                             const __half* __restrict__ g,
                                             const float* __restrict__ bias,
                                             float* __restrict__ out) {
    const int v = blockIdx.x * 4 + (threadIdx.x >> 6);
    if (v >= NN) return;
    const int lane = threadIdx.x & 63;
    const int sub  = lane & 15;
    const int slot = lane >> 4;
    const int beg = row_start[v];
    const int cnt = row_start[v + 1] - beg;
    int pre = 0;
    if (lane < cnt) pre = (int)pack2[beg + lane];
    const int n0 = cnt < 64 ? cnt : 64;
    float4 acc = make_float4(0.f, 0.f, 0.f, 0.f);

    int k = 0;
    for (; k + 8 <= n0; k += 8) {
        int sA = __shfl(pre, k + slot);
        int sB = __shfl(pre, k + 4 + slot);
        uint2 rA = *(const uint2*)(g + sA * HID + sub * 4);
        uint2 rB = *(const uint2*)(g + sB * HID + sub * 4);
        float2 a0 = __half22float2(*(const __half2*)&rA.x);
        float2 a1 = __half22float2(*(const __half2*)&rA.y);
        float2 b0 = __half22float2(*(const __half2*)&rB.x);
        float2 b1 = __half22float2(*(const __half2*)&rB.y);
        acc.x += a0.x + b0.x; acc.y += a0.y + b0.y;
        acc.z += a1.x + b1.x; acc.w += a1.y + b1.y;
    }
    for (; k < n0; k += 4) {
        int idx  = k + slot;
        int idxc = idx < n0 ? idx : 0;
        int s = __shfl(pre, idxc);
        if (idx < n0) {
            uint2 r = *(const uint2*)(g + s * HID + sub * 4);
            float2 a0 = __half22float2(*(const __half2*)&r.x);
            float2 a1 = __half22float2(*(const __half2*)&r.y);
            acc.x += a0.x; acc.y += a0.y; acc.z += a1.x; acc.w += a1.y;
        }
    }
    for (int kk = 64 + slot; kk < cnt; kk += 4) {
        int s = (int)pack2[beg + kk];
        uint2 r = *(const uint2*)(g + s * HID + sub * 4);
        float2 a0 = __half22float2(*(const __half2*)&r.x);
        float2 a1 = __half22float2(*(const __half2*)&r.y);
        acc.x += a0.x; acc.y += a0.y; acc.z += a1.x; acc.w += a1.y;
    }
#pragma unroll
    for (int mm = 16; mm <= 32; mm <<= 1) {
        acc.x += __shfl_xor(acc.x, mm);
        acc.y += __shfl_xor(acc.y, mm);
        acc.z += __shfl_xor(acc.z, mm);
        acc.w += __shfl_xor(acc.w, mm);
    }
    if (slot == 0) {
        const float dv = dinv[v];
        uint2 sr = *(const uint2*)(g + v * HID + sub * 4);
        float2 s0 = __half22float2(*(const __half2*)&sr.x);
        float2 s1 = __half22float2(*(const __half2*)&sr.y);
        float4 bv = *(const float4*)(bias + sub * 4);
        float4 o;
        o.x = dv * (acc.x + s0.x) + bv.x;
        o.y = dv * (acc.y + s0.y) + bv.y;
        o.z = dv * (acc.z + s1.x) + bv.z;
        o.w = dv * (acc.w + s1.y) + bv.w;
        *(float4*)(out + v * HID + sub * 4) = o;
    }
}

// ---------------- launch ----------------
extern "C" void kernel_launch(void* const* d_in, const int* in_sizes, int n_in,
                              void* d_out, int out_size, void* d_ws, size_t ws_size,
                              hipStream_t stream) {
    const float* x  = (const float*)d_in[0];
    const int*   ei = (const int*)d_in[1];
    const float* W1 = (const float*)d_in[2];
    const float* b1 = (const float*)d_in[3];
    const float* W2 = (const float*)d_in[4];
    const float* b2 = (const float*)d_in[5];
    float* out = (float*)d_out;
    (void)in_sizes; (void)n_in; (void)out_size; (void)ws_size;

    const int* src = ei;
    const int* dst = ei + NE;

    // Workspace (~40 MB of the 256 MiB ws):
    char* ws = (char*)d_ws;
    int*      total     = (int*)(ws + 0x000000);     // 4 KB
    int*      base      = (int*)(ws + 0x001000);     // 4 KB
    int*      gcur      = (int*)(ws + 0x002000);     // 4 KB
    __half*   Whp1      = (__half*)(ws + 0x004000);  // 16 KB (frag-major W1)
    __half*   Whp2      = (__half*)(ws + 0x008000);  // 8 KB  (frag-major W2)
    float*    dinv      = (float*)(ws + 0x010000);   // 400 KB
    int*      row_start = (int*)(ws + 0x080000);     // 400 KB + 4
    unsigned* pack1     = (unsigned*)(ws + 0x100000);  // 5 MB
    unsigned* pack2     = (unsigned*)(ws + 0x600000);  // 5 MB
    __half*   g1        = (__half*)(ws + 0x0B00000);   // 12.8 MB (fp16)
    __half*   g2        = (__half*)(ws + 0x1900000);   // 12.8 MB (fp16)

    // prep (W packs + bin zero) and CSR build
    k_prep<<<7, 256, 0, stream>>>(W1, W2, Whp1, Whp2, total);
    k_hist<<<128, 256, 0, stream>>>(dst, total);
    k_scan<<<1, NBP, 0, stream>>>(total, base, gcur);
    k_bin<<<BIN_BLOCKS, 1024, 0, stream>>>(src, dst, gcur, pack1);
    k_sort<<<NB, 256, 0, stream>>>(pack1, base, pack2, row_start, dinv);

    // layer 1 GEMM: g1 = fp16(dinv*(x @ W1))
    k_mm<KDIM><<<(NN + 63) / 64, 256, 0, stream>>>(x, Whp1, dinv, g1);
    // fused: agg1 (+b1, relu) -> mm2 -> g2 = fp16(dinv*(relu(out1) @ W2))
    k_aggmm<<<NN / 16, 256, 0, stream>>>(pack2, row_start, dinv, g1, b1, Whp2, g2);
    // final agg: out = dinv*(sum g2 + g2_self) + b2
    k_agg<<<(NN + 3) / 4, 256, 0, stream>>>(pack2, row_start, dinv, g2, b2, out);
}